// Round 9
// baseline (341.833 us; speedup 1.0000x reference)
//
#include <hip/hip_runtime.h>
#include <hip/hip_bf16.h>

#define NN   100000
#define NE   50000
#define NNZP 1600000
#define DD   128

#define EBK  512
#define NBE  ((NE + EBK - 1) / EBK)             // 98
#define VBK  512
#define NBV  ((NN + VBK - 1) / VBK)             // 196
#define NBT  (NBE + NBV)                        // 294
#define CH   2048                               // pairs per hist block
#define NCHB ((NNZP + CH - 1) / CH)             // 782
#define CH2  6250                               // pairs per scatter block (256 * 6250 == NNZP)

typedef __attribute__((ext_vector_type(8))) short bf16x8;
typedef __attribute__((ext_vector_type(4))) float f32x4;
typedef __attribute__((ext_vector_type(2))) unsigned int u32x2;

__device__ __forceinline__ ushort f2bf(float f) {
    __hip_bfloat16 h = __float2bfloat16(f);
    return *reinterpret_cast<ushort*>(&h);
}
__device__ __forceinline__ void accP(u32x2 u, float& ax, float& ay, float& az, float& aw) {
    ax += __uint_as_float(u.x << 16);
    ay += __uint_as_float(u.x & 0xffff0000u);
    az += __uint_as_float(u.y << 16);
    aw += __uint_as_float(u.y & 0xffff0000u);
}
__device__ __forceinline__ u32x2 ldg_u2(const ushort* p) {          // cached (gather)
    return *reinterpret_cast<const u32x2*>(p);
}
__device__ __forceinline__ u32x2 ldnt_u2(const ushort* p) {         // non-temporal
    return __builtin_nontemporal_load(reinterpret_cast<const u32x2*>(p));
}
__device__ __forceinline__ int ldnt_i(const int* p) {
    return __builtin_nontemporal_load(p);
}

// ------- K1: fused per-bucket histogram (LDS-privatized) + Wt convert -------
__global__ __launch_bounds__(256) void hist_convert(const int* __restrict__ vertex,
                                                    const int* __restrict__ edges,
                                                    int* __restrict__ gEcnt,
                                                    int* __restrict__ gVcnt,
                                                    const float* __restrict__ W,
                                                    ushort* __restrict__ Wt) {
    __shared__ int cE[NBE], cV[NBV];
    const int t = threadIdx.x;
    if (blockIdx.x >= NCHB) {       // tail blocks: Wt16[n][k] = bf16(W[k][n])
        int i = (blockIdx.x - NCHB) * 256 + t;
        if (i < DD * DD) { int k = i >> 7, n = i & 127; Wt[n * DD + k] = f2bf(W[i]); }
        return;
    }
    for (int i = t; i < NBE; i += 256) cE[i] = 0;
    for (int i = t; i < NBV; i += 256) cV[i] = 0;
    __syncthreads();
    int base = blockIdx.x * CH + t * 8;
    if (base + 7 < NNZP) {
        int4 e0 = *reinterpret_cast<const int4*>(edges + base);
        int4 e1 = *reinterpret_cast<const int4*>(edges + base + 4);
        int4 v0 = *reinterpret_cast<const int4*>(vertex + base);
        int4 v1 = *reinterpret_cast<const int4*>(vertex + base + 4);
        atomicAdd(&cE[e0.x >> 9], 1); atomicAdd(&cE[e0.y >> 9], 1);
        atomicAdd(&cE[e0.z >> 9], 1); atomicAdd(&cE[e0.w >> 9], 1);
        atomicAdd(&cE[e1.x >> 9], 1); atomicAdd(&cE[e1.y >> 9], 1);
        atomicAdd(&cE[e1.z >> 9], 1); atomicAdd(&cE[e1.w >> 9], 1);
        atomicAdd(&cV[v0.x >> 9], 1); atomicAdd(&cV[v0.y >> 9], 1);
        atomicAdd(&cV[v0.z >> 9], 1); atomicAdd(&cV[v0.w >> 9], 1);
        atomicAdd(&cV[v1.x >> 9], 1); atomicAdd(&cV[v1.y >> 9], 1);
        atomicAdd(&cV[v1.z >> 9], 1); atomicAdd(&cV[v1.w >> 9], 1);
    }
    __syncthreads();
    for (int i = t; i < NBE; i += 256) if (cE[i]) atomicAdd(&gEcnt[i], cE[i]);
    for (int i = t; i < NBV; i += 256) if (cV[i]) atomicAdd(&gVcnt[i], cV[i]);
}

// ---------------- K2: Xp16 = bf16( X @ W ) via MFMA (2 rowTiles/wave) ----------------
__global__ __launch_bounds__(256) void gemm_mfma(const float* __restrict__ X,
                                                 const ushort* __restrict__ Wt,
                                                 ushort* __restrict__ Xp16) {
    __shared__ char WtL[DD * DD * 2];   // 32 KB, XOR-swizzled 16B chunks
    for (int c = threadIdx.x; c < 2048; c += 256) {
        int n = c >> 4, kc = c & 15;
        int dst = (n * 256 + kc * 16) ^ ((n & 7) << 4);
        *reinterpret_cast<int4*>(WtL + dst) = reinterpret_cast<const int4*>(Wt)[c];
    }
    __syncthreads();
    int wave = threadIdx.x >> 6;
    int lane = threadIdx.x & 63;
    int r = lane & 15, half = lane >> 4;
    #pragma unroll
    for (int rt = 0; rt < 2; ++rt) {
        int rowTile = blockIdx.x * 8 + wave * 2 + rt;
        if (rowTile >= NN / 16) break;
        const float* xrow = X + (size_t)(rowTile * 16 + r) * DD;
        f32x4 acc[8];
        #pragma unroll
        for (int nt = 0; nt < 8; ++nt) acc[nt] = (f32x4)(0.f);
        #pragma unroll
        for (int kk = 0; kk < DD; kk += 32) {
            int kbase = kk + half * 8;
            float4 xa = *reinterpret_cast<const float4*>(xrow + kbase);
            float4 xb = *reinterpret_cast<const float4*>(xrow + kbase + 4);
            bf16x8 a;
            a[0] = (short)f2bf(xa.x); a[1] = (short)f2bf(xa.y);
            a[2] = (short)f2bf(xa.z); a[3] = (short)f2bf(xa.w);
            a[4] = (short)f2bf(xb.x); a[5] = (short)f2bf(xb.y);
            a[6] = (short)f2bf(xb.z); a[7] = (short)f2bf(xb.w);
            #pragma unroll
            for (int nt = 0; nt < 8; ++nt) {
                int n = nt * 16 + r;
                int off = (n * 256 + kbase * 2) ^ ((n & 7) << 4);
                bf16x8 b = *reinterpret_cast<const bf16x8*>(WtL + off);
                acc[nt] = __builtin_amdgcn_mfma_f32_16x16x32_bf16(a, b, acc[nt], 0, 0, 0);
            }
        }
        int row0 = rowTile * 16 + half * 4;   // C/D: col=lane&15, row=(lane>>4)*4+q
        #pragma unroll
        for (int nt = 0; nt < 8; ++nt)
            #pragma unroll
            for (int q = 0; q < 4; ++q)
                Xp16[(size_t)(row0 + q) * DD + nt * 16 + r] = f2bf(acc[nt][q]);
    }
}

// ------- K3: scan 294 bucket counts -> bases + cursors; fixed tails -------
__global__ __launch_bounds__(512) void bucket_scan(const int* __restrict__ gCnt,  // [NBT]
                                                   int* __restrict__ eBase,       // [NBE+1]
                                                   int* __restrict__ vBase,       // [NBV+1]
                                                   int* __restrict__ gEcur,
                                                   int* __restrict__ gVcur,
                                                   int* __restrict__ eoff,
                                                   int* __restrict__ voff) {
    __shared__ int sh[512];
    int t = threadIdx.x;
    int v = (t < NBT) ? gCnt[t] : 0;
    sh[t] = v;
    __syncthreads();
    for (int d = 1; d < 512; d <<= 1) {
        int x = (t >= d) ? sh[t - d] : 0;
        __syncthreads();
        sh[t] += x;
        __syncthreads();
    }
    int excl = sh[t] - v;     // exclusive scan; edge buckets sum to NNZP
    if (t < NBE)      { eBase[t] = excl;        gEcur[t] = excl; }
    else if (t < NBT) { vBase[t - NBE] = excl - NNZP; gVcur[t - NBE] = excl - NNZP; }
    if (t == 0) { eBase[NBE] = NNZP; vBase[NBV] = NNZP; eoff[NE] = NNZP; voff[NN] = NNZP; }
}

// ------- K4: 2-pass bucket scatter: count -> reserve -> place (packed payloads) -------
// ebuckP[i] = (e&511)<<17 | v   (9b local edge + 17b vertex)
// vbuckP[i] = (v&511)<<16 | e   (9b local vertex + 16b edge)
__global__ __launch_bounds__(256) void bucket_scatter2(const int* __restrict__ vertex,
                                                       const int* __restrict__ edges,
                                                       int* __restrict__ gEcur,
                                                       int* __restrict__ gVcur,
                                                       unsigned int* __restrict__ ebuckP,
                                                       unsigned int* __restrict__ vbuckP) {
    __shared__ int cE[NBE], bE[NBE], cV[NBV], bV[NBV];
    const int t = threadIdx.x;
    const int base = blockIdx.x * CH2;          // 256*CH2 == NNZP
    for (int i = t; i < NBE; i += 256) cE[i] = 0;
    for (int i = t; i < NBV; i += 256) cV[i] = 0;
    __syncthreads();
    // pass 1: count
    for (int i = t; i < CH2 / 2; i += 256) {
        int2 e2 = *reinterpret_cast<const int2*>(edges + base + i * 2);
        int2 v2 = *reinterpret_cast<const int2*>(vertex + base + i * 2);
        atomicAdd(&cE[e2.x >> 9], 1); atomicAdd(&cE[e2.y >> 9], 1);
        atomicAdd(&cV[v2.x >> 9], 1); atomicAdd(&cV[v2.y >> 9], 1);
    }
    __syncthreads();
    // reserve contiguous runs
    for (int i = t; i < NBE; i += 256) {
        int c = cE[i];
        bE[i] = c ? atomicAdd(&gEcur[i], c) : 0;
        cE[i] = 0;
    }
    for (int i = t; i < NBV; i += 256) {
        int c = cV[i];
        bV[i] = c ? atomicAdd(&gVcur[i], c) : 0;
        cV[i] = 0;
    }
    __syncthreads();
    // pass 2: place packed payloads (re-read, L2-hot)
    for (int i = t; i < CH2 / 2; i += 256) {
        int2 e2 = *reinterpret_cast<const int2*>(edges + base + i * 2);
        int2 v2 = *reinterpret_cast<const int2*>(vertex + base + i * 2);
        int pe0 = bE[e2.x >> 9] + atomicAdd(&cE[e2.x >> 9], 1);
        __builtin_nontemporal_store(((unsigned)(e2.x & 511) << 17) | (unsigned)v2.x, ebuckP + pe0);
        int pe1 = bE[e2.y >> 9] + atomicAdd(&cE[e2.y >> 9], 1);
        __builtin_nontemporal_store(((unsigned)(e2.y & 511) << 17) | (unsigned)v2.y, ebuckP + pe1);
        int pv0 = bV[v2.x >> 9] + atomicAdd(&cV[v2.x >> 9], 1);
        __builtin_nontemporal_store(((unsigned)(v2.x & 511) << 16) | (unsigned)e2.x, vbuckP + pv0);
        int pv1 = bV[v2.y >> 9] + atomicAdd(&cV[v2.y >> 9], 1);
        __builtin_nontemporal_store(((unsigned)(v2.y & 511) << 16) | (unsigned)e2.y, vbuckP + pv1);
    }
}

// ------- K5: per bucket: LDS per-id hist + scan -> eoff/voff, then place ----
__global__ __launch_bounds__(256) void place_buckets2(const unsigned int* __restrict__ ebuckP,
                                                      const unsigned int* __restrict__ vbuckP,
                                                      const int* __restrict__ eBase,
                                                      const int* __restrict__ vBase,
                                                      int* __restrict__ eoff,
                                                      int* __restrict__ voff,
                                                      int* __restrict__ vlist,
                                                      int* __restrict__ elist) {
    __shared__ int cnt[EBK];
    __shared__ int wsum[4];
    const int t = threadIdx.x;
    int b = blockIdx.x;
    const unsigned int* buck; int id0, nid, start, end; int* off; int* lst;
    int sh_amt; unsigned msk;
    if (b < NBE) {
        buck = ebuckP; id0 = b * EBK; nid = min(EBK, NE - id0);
        start = eBase[b]; end = eBase[b + 1]; off = eoff; lst = vlist;
        sh_amt = 17; msk = 0x1FFFFu;
    } else {
        b -= NBE;
        buck = vbuckP; id0 = b * VBK; nid = min(VBK, NN - id0);
        start = vBase[b]; end = vBase[b + 1]; off = voff; lst = elist;
        sh_amt = 16; msk = 0xFFFFu;
    }
    for (int i = t; i < nid; i += 256) cnt[i] = 0;
    __syncthreads();
    // pass 1: per-id histogram of this bucket's run
    for (int i = start + t; i < end; i += 256) {
        unsigned p = __builtin_nontemporal_load(buck + i);
        atomicAdd(&cnt[p >> sh_amt], 1);
    }
    __syncthreads();
    int c0 = (2 * t     < nid) ? cnt[2 * t]     : 0;
    int c1 = (2 * t + 1 < nid) ? cnt[2 * t + 1] : 0;
    int s = c0 + c1;
    int inc = s;
    #pragma unroll
    for (int d = 1; d < 64; d <<= 1) {
        int x = __shfl_up(inc, d, 64);
        if ((t & 63) >= d) inc += x;
    }
    if ((t & 63) == 63) wsum[t >> 6] = inc;
    __syncthreads();
    int wid = t >> 6, wbase = 0;
    #pragma unroll
    for (int w = 0; w < 3; ++w) if (w < wid) wbase += wsum[w];
    int excl = start + wbase + (inc - s);
    if (2 * t     < nid) off[id0 + 2 * t]     = excl;
    if (2 * t + 1 < nid) off[id0 + 2 * t + 1] = excl + c0;
    __syncthreads();
    if (2 * t     < nid) cnt[2 * t]     = excl;
    if (2 * t + 1 < nid) cnt[2 * t + 1] = excl + c0;
    __syncthreads();
    // pass 2: place payloads at final CSR slots
    for (int i = start + t; i < end; i += 256) {
        unsigned p = __builtin_nontemporal_load(buck + i);
        lst[atomicAdd(&cnt[p >> sh_amt], 1)] = (int)(p & msk);
    }
}

// ---------------- K6: Xe[e] = mean of Xp16 rows; also Xe16 ----------------
__global__ __launch_bounds__(256) void edge_gather(const ushort* __restrict__ Xp16,
                                                   const int* __restrict__ eoff,
                                                   const int* __restrict__ vlist,
                                                   float* __restrict__ Xe,
                                                   ushort* __restrict__ Xe16) {
    int e = blockIdx.x * 8 + (threadIdx.x >> 5);
    if (e >= NE) return;
    int lane = threadIdx.x & 31;
    int start = eoff[e], end = eoff[e + 1];
    float ax = 0.f, ay = 0.f, az = 0.f, aw = 0.f;
    int j = start;
    for (; j + 7 < end; j += 8) {
        int v0 = ldnt_i(vlist + j),     v1 = ldnt_i(vlist + j + 1);
        int v2 = ldnt_i(vlist + j + 2), v3 = ldnt_i(vlist + j + 3);
        int v4 = ldnt_i(vlist + j + 4), v5 = ldnt_i(vlist + j + 5);
        int v6 = ldnt_i(vlist + j + 6), v7 = ldnt_i(vlist + j + 7);
        u32x2 u0 = ldg_u2(Xp16 + (size_t)v0 * DD + lane * 4);
        u32x2 u1 = ldg_u2(Xp16 + (size_t)v1 * DD + lane * 4);
        u32x2 u2 = ldg_u2(Xp16 + (size_t)v2 * DD + lane * 4);
        u32x2 u3 = ldg_u2(Xp16 + (size_t)v3 * DD + lane * 4);
        u32x2 u4 = ldg_u2(Xp16 + (size_t)v4 * DD + lane * 4);
        u32x2 u5 = ldg_u2(Xp16 + (size_t)v5 * DD + lane * 4);
        u32x2 u6 = ldg_u2(Xp16 + (size_t)v6 * DD + lane * 4);
        u32x2 u7 = ldg_u2(Xp16 + (size_t)v7 * DD + lane * 4);
        accP(u0, ax, ay, az, aw); accP(u1, ax, ay, az, aw);
        accP(u2, ax, ay, az, aw); accP(u3, ax, ay, az, aw);
        accP(u4, ax, ay, az, aw); accP(u5, ax, ay, az, aw);
        accP(u6, ax, ay, az, aw); accP(u7, ax, ay, az, aw);
    }
    for (; j < end; ++j) {
        u32x2 u = ldg_u2(Xp16 + (size_t)ldnt_i(vlist + j) * DD + lane * 4);
        accP(u, ax, ay, az, aw);
    }
    float inv = 1.0f / fmaxf((float)(end - start), 1.0f);
    f32x4 o; o[0] = ax * inv; o[1] = ay * inv; o[2] = az * inv; o[3] = aw * inv;
    __builtin_nontemporal_store(o, reinterpret_cast<f32x4*>(Xe + (size_t)e * DD + lane * 4));
    ushort4 h;
    h.x = f2bf(o[0]); h.y = f2bf(o[1]); h.z = f2bf(o[2]); h.w = f2bf(o[3]);
    *reinterpret_cast<ushort4*>(Xe16 + (size_t)e * DD + lane * 4) = h;
}

// -------- K7: Xv = sum Xe16 rows; out = normalize((1+eps)*Xp + Xv) --------
__global__ __launch_bounds__(256) void vertex_gather_out(const ushort* __restrict__ Xp16,
                                                         const ushort* __restrict__ Xe16,
                                                         const int* __restrict__ voff,
                                                         const int* __restrict__ elist,
                                                         const float* __restrict__ eps,
                                                         float* __restrict__ Out) {
    int v = blockIdx.x * 8 + (threadIdx.x >> 5);
    if (v >= NN) return;
    int lane = threadIdx.x & 31;
    int start = voff[v], end = voff[v + 1];
    float ax = 0.f, ay = 0.f, az = 0.f, aw = 0.f;
    int j = start;
    for (; j + 7 < end; j += 8) {
        int e0 = ldnt_i(elist + j),     e1 = ldnt_i(elist + j + 1);
        int e2 = ldnt_i(elist + j + 2), e3 = ldnt_i(elist + j + 3);
        int e4 = ldnt_i(elist + j + 4), e5 = ldnt_i(elist + j + 5);
        int e6 = ldnt_i(elist + j + 6), e7 = ldnt_i(elist + j + 7);
        u32x2 u0 = ldg_u2(Xe16 + (size_t)e0 * DD + lane * 4);
        u32x2 u1 = ldg_u2(Xe16 + (size_t)e1 * DD + lane * 4);
        u32x2 u2 = ldg_u2(Xe16 + (size_t)e2 * DD + lane * 4);
        u32x2 u3 = ldg_u2(Xe16 + (size_t)e3 * DD + lane * 4);
        u32x2 u4 = ldg_u2(Xe16 + (size_t)e4 * DD + lane * 4);
        u32x2 u5 = ldg_u2(Xe16 + (size_t)e5 * DD + lane * 4);
        u32x2 u6 = ldg_u2(Xe16 + (size_t)e6 * DD + lane * 4);
        u32x2 u7 = ldg_u2(Xe16 + (size_t)e7 * DD + lane * 4);
        accP(u0, ax, ay, az, aw); accP(u1, ax, ay, az, aw);
        accP(u2, ax, ay, az, aw); accP(u3, ax, ay, az, aw);
        accP(u4, ax, ay, az, aw); accP(u5, ax, ay, az, aw);
        accP(u6, ax, ay, az, aw); accP(u7, ax, ay, az, aw);
    }
    for (; j < end; ++j) {
        u32x2 u = ldg_u2(Xe16 + (size_t)ldnt_i(elist + j) * DD + lane * 4);
        accP(u, ax, ay, az, aw);
    }
    float g = 1.0f + eps[0];
    u32x2 xp = ldnt_u2(Xp16 + (size_t)v * DD + lane * 4);   // sequential, read-once
    f32x4 o;
    o[0] = fmaf(g, __uint_as_float(xp.x << 16),         ax);
    o[1] = fmaf(g, __uint_as_float(xp.x & 0xffff0000u), ay);
    o[2] = fmaf(g, __uint_as_float(xp.y << 16),         az);
    o[3] = fmaf(g, __uint_as_float(xp.y & 0xffff0000u), aw);
    float ss = o[0] * o[0] + o[1] * o[1] + o[2] * o[2] + o[3] * o[3];
    #pragma unroll
    for (int off = 1; off < 32; off <<= 1) ss += __shfl_xor(ss, off, 64);
    float inv = 1.0f / fmaxf(sqrtf(ss), 1e-12f);
    o[0] *= inv; o[1] *= inv; o[2] *= inv; o[3] *= inv;
    __builtin_nontemporal_store(o, reinterpret_cast<f32x4*>(Out + (size_t)v * DD + lane * 4));
}

extern "C" void kernel_launch(void* const* d_in, const int* in_sizes, int n_in,
                              void* d_out, int out_size, void* d_ws, size_t ws_size,
                              hipStream_t stream) {
    const float* X      = (const float*)d_in[0];
    const float* W      = (const float*)d_in[1];
    const float* eps    = (const float*)d_in[2];
    const int*   vertex = (const int*)d_in[3];
    const int*   edges  = (const int*)d_in[4];

    float* out = (float*)d_out;                 // [N,D] — scratch for buckets until K7
    float* Xe  = out + (size_t)NN * DD;         // [E,D]

    // packed bucket arrays live in the 'out' region (dead until vertex_gather_out)
    unsigned int* ebuckP = (unsigned int*)out;  // NNZ ints = 6.4 MB
    unsigned int* vbuckP = ebuckP + NNZP;       // NNZ ints = 6.4 MB (total 12.8 <= 51.2)

    // workspace layout (~52 MB)
    ushort* Xp16 = (ushort*)d_ws;                        // N*D bf16
    ushort* Xe16 = Xp16 + (size_t)NN * DD;               // E*D bf16
    ushort* Wt16 = Xe16 + (size_t)NE * DD;               // D*D bf16
    int*    eoff = (int*)(Wt16 + DD * DD);               // E+1
    int*    voff = eoff + NE + 1;                        // N+1
    int*    vlist = voff + NN + 1;                       // NNZ
    int*    elist = vlist + NNZP;                        // NNZ
    int*    gEcnt = elist + NNZP;                        // NBE   (contiguous with gVcnt)
    int*    gVcnt = gEcnt + NBE;                         // NBV
    int*    gEcur = gVcnt + NBV;                         // NBE
    int*    gVcur = gEcur + NBE;                         // NBV
    int*    eBase = gVcur + NBV;                         // NBE+1
    int*    vBase = eBase + NBE + 1;                     // NBV+1

    hipMemsetAsync(gEcnt, 0, (size_t)NBT * sizeof(int), stream);

    hist_convert<<<NCHB + 64, 256, 0, stream>>>(vertex, edges, gEcnt, gVcnt, W, Wt16);
    gemm_mfma<<<(NN / 16 + 7) / 8, 256, 0, stream>>>(X, Wt16, Xp16);
    bucket_scan<<<1, 512, 0, stream>>>(gEcnt, eBase, vBase, gEcur, gVcur, eoff, voff);
    bucket_scatter2<<<256, 256, 0, stream>>>(vertex, edges, gEcur, gVcur, ebuckP, vbuckP);
    place_buckets2<<<NBT, 256, 0, stream>>>(ebuckP, vbuckP, eBase, vBase, eoff, voff, vlist, elist);
    edge_gather<<<NE / 8, 256, 0, stream>>>(Xp16, eoff, vlist, Xe, Xe16);
    vertex_gather_out<<<NN / 8, 256, 0, stream>>>(Xp16, Xe16, voff, elist, eps, out);
}

// Round 10
// 252.414 us; speedup vs baseline: 1.3543x; 1.3543x over previous
//
#include <hip/hip_runtime.h>
#include <hip/hip_bf16.h>

#define NN   100000
#define NE   50000
#define NNZP 1600000
#define DD   128

#define EBK  512
#define NBE  ((NE + EBK - 1) / EBK)             // 98
#define VBK  512
#define NBV  ((NN + VBK - 1) / VBK)             // 196
#define NBT  (NBE + NBV)                        // 294
#define CH   2048                               // pairs per hist block
#define NCHB ((NNZP + CH - 1) / CH)             // 782
#define CH2  3200                               // pairs per scatter block (500 * 3200 == NNZP)
#define NSB  500

typedef __attribute__((ext_vector_type(8))) short bf16x8;
typedef __attribute__((ext_vector_type(4))) float f32x4;
typedef __attribute__((ext_vector_type(2))) unsigned int u32x2;

__device__ __forceinline__ ushort f2bf(float f) {
    __hip_bfloat16 h = __float2bfloat16(f);
    return *reinterpret_cast<ushort*>(&h);
}
__device__ __forceinline__ void accP(u32x2 u, float& ax, float& ay, float& az, float& aw) {
    ax += __uint_as_float(u.x << 16);
    ay += __uint_as_float(u.x & 0xffff0000u);
    az += __uint_as_float(u.y << 16);
    aw += __uint_as_float(u.y & 0xffff0000u);
}
__device__ __forceinline__ u32x2 ldg_u2(const ushort* p) {          // cached (gather)
    return *reinterpret_cast<const u32x2*>(p);
}

// ------- K1: fused per-bucket histogram (LDS-privatized) + Wt convert -------
__global__ __launch_bounds__(256) void hist_convert(const int* __restrict__ vertex,
                                                    const int* __restrict__ edges,
                                                    int* __restrict__ gEcnt,
                                                    int* __restrict__ gVcnt,
                                                    const float* __restrict__ W,
                                                    ushort* __restrict__ Wt) {
    __shared__ int cE[NBE], cV[NBV];
    const int t = threadIdx.x;
    if (blockIdx.x >= NCHB) {       // tail blocks: Wt16[n][k] = bf16(W[k][n])
        int i = (blockIdx.x - NCHB) * 256 + t;
        if (i < DD * DD) { int k = i >> 7, n = i & 127; Wt[n * DD + k] = f2bf(W[i]); }
        return;
    }
    for (int i = t; i < NBE; i += 256) cE[i] = 0;
    for (int i = t; i < NBV; i += 256) cV[i] = 0;
    __syncthreads();
    int base = blockIdx.x * CH + t * 8;
    if (base + 7 < NNZP) {
        int4 e0 = *reinterpret_cast<const int4*>(edges + base);
        int4 e1 = *reinterpret_cast<const int4*>(edges + base + 4);
        int4 v0 = *reinterpret_cast<const int4*>(vertex + base);
        int4 v1 = *reinterpret_cast<const int4*>(vertex + base + 4);
        atomicAdd(&cE[e0.x >> 9], 1); atomicAdd(&cE[e0.y >> 9], 1);
        atomicAdd(&cE[e0.z >> 9], 1); atomicAdd(&cE[e0.w >> 9], 1);
        atomicAdd(&cE[e1.x >> 9], 1); atomicAdd(&cE[e1.y >> 9], 1);
        atomicAdd(&cE[e1.z >> 9], 1); atomicAdd(&cE[e1.w >> 9], 1);
        atomicAdd(&cV[v0.x >> 9], 1); atomicAdd(&cV[v0.y >> 9], 1);
        atomicAdd(&cV[v0.z >> 9], 1); atomicAdd(&cV[v0.w >> 9], 1);
        atomicAdd(&cV[v1.x >> 9], 1); atomicAdd(&cV[v1.y >> 9], 1);
        atomicAdd(&cV[v1.z >> 9], 1); atomicAdd(&cV[v1.w >> 9], 1);
    }
    __syncthreads();
    for (int i = t; i < NBE; i += 256) if (cE[i]) atomicAdd(&gEcnt[i], cE[i]);
    for (int i = t; i < NBV; i += 256) if (cV[i]) atomicAdd(&gVcnt[i], cV[i]);
}

// ---------------- K2: Xp16 = bf16( X @ W ) via MFMA (2 rowTiles/wave) ----------------
__global__ __launch_bounds__(256) void gemm_mfma(const float* __restrict__ X,
                                                 const ushort* __restrict__ Wt,
                                                 ushort* __restrict__ Xp16) {
    __shared__ char WtL[DD * DD * 2];   // 32 KB, XOR-swizzled 16B chunks
    for (int c = threadIdx.x; c < 2048; c += 256) {
        int n = c >> 4, kc = c & 15;
        int dst = (n * 256 + kc * 16) ^ ((n & 7) << 4);
        *reinterpret_cast<int4*>(WtL + dst) = reinterpret_cast<const int4*>(Wt)[c];
    }
    __syncthreads();
    int wave = threadIdx.x >> 6;
    int lane = threadIdx.x & 63;
    int r = lane & 15, half = lane >> 4;
    #pragma unroll
    for (int rt = 0; rt < 2; ++rt) {
        int rowTile = blockIdx.x * 8 + wave * 2 + rt;
        if (rowTile >= NN / 16) break;
        const float* xrow = X + (size_t)(rowTile * 16 + r) * DD;
        f32x4 acc[8];
        #pragma unroll
        for (int nt = 0; nt < 8; ++nt) acc[nt] = (f32x4)(0.f);
        #pragma unroll
        for (int kk = 0; kk < DD; kk += 32) {
            int kbase = kk + half * 8;
            float4 xa = *reinterpret_cast<const float4*>(xrow + kbase);
            float4 xb = *reinterpret_cast<const float4*>(xrow + kbase + 4);
            bf16x8 a;
            a[0] = (short)f2bf(xa.x); a[1] = (short)f2bf(xa.y);
            a[2] = (short)f2bf(xa.z); a[3] = (short)f2bf(xa.w);
            a[4] = (short)f2bf(xb.x); a[5] = (short)f2bf(xb.y);
            a[6] = (short)f2bf(xb.z); a[7] = (short)f2bf(xb.w);
            #pragma unroll
            for (int nt = 0; nt < 8; ++nt) {
                int n = nt * 16 + r;
                int off = (n * 256 + kbase * 2) ^ ((n & 7) << 4);
                bf16x8 b = *reinterpret_cast<const bf16x8*>(WtL + off);
                acc[nt] = __builtin_amdgcn_mfma_f32_16x16x32_bf16(a, b, acc[nt], 0, 0, 0);
            }
        }
        int row0 = rowTile * 16 + half * 4;   // C/D: col=lane&15, row=(lane>>4)*4+q
        #pragma unroll
        for (int nt = 0; nt < 8; ++nt)
            #pragma unroll
            for (int q = 0; q < 4; ++q)
                Xp16[(size_t)(row0 + q) * DD + nt * 16 + r] = f2bf(acc[nt][q]);
    }
}

// ------- K3: scan 294 bucket counts -> bases + cursors; fixed tails -------
__global__ __launch_bounds__(512) void bucket_scan(const int* __restrict__ gCnt,  // [NBT]
                                                   int* __restrict__ eBase,       // [NBE+1]
                                                   int* __restrict__ vBase,       // [NBV+1]
                                                   int* __restrict__ gEcur,
                                                   int* __restrict__ gVcur,
                                                   int* __restrict__ eoff,
                                                   int* __restrict__ voff) {
    __shared__ int sh[512];
    int t = threadIdx.x;
    int v = (t < NBT) ? gCnt[t] : 0;
    sh[t] = v;
    __syncthreads();
    for (int d = 1; d < 512; d <<= 1) {
        int x = (t >= d) ? sh[t - d] : 0;
        __syncthreads();
        sh[t] += x;
        __syncthreads();
    }
    int excl = sh[t] - v;     // exclusive scan; edge buckets sum to NNZP
    if (t < NBE)      { eBase[t] = excl;        gEcur[t] = excl; }
    else if (t < NBT) { vBase[t - NBE] = excl - NNZP; gVcur[t - NBE] = excl - NNZP; }
    if (t == 0) { eBase[NBE] = NNZP; vBase[NBV] = NNZP; eoff[NE] = NNZP; voff[NN] = NNZP; }
}

// ------- K4: 2-pass bucket scatter: count -> reserve -> place (packed, cached stores) ----
// ebuckP[i] = (e&511)<<17 | v   (9b local edge + 17b vertex)
// vbuckP[i] = (v&511)<<16 | e   (9b local vertex + 16b edge)
__global__ __launch_bounds__(256) void bucket_scatter2(const int* __restrict__ vertex,
                                                       const int* __restrict__ edges,
                                                       int* __restrict__ gEcur,
                                                       int* __restrict__ gVcur,
                                                       unsigned int* __restrict__ ebuckP,
                                                       unsigned int* __restrict__ vbuckP) {
    __shared__ int cE[NBE], bE[NBE], cV[NBV], bV[NBV];
    const int t = threadIdx.x;
    const int base = blockIdx.x * CH2;          // NSB*CH2 == NNZP
    for (int i = t; i < NBE; i += 256) cE[i] = 0;
    for (int i = t; i < NBV; i += 256) cV[i] = 0;
    __syncthreads();
    // pass 1: count
    for (int i = t; i < CH2 / 2; i += 256) {
        int2 e2 = *reinterpret_cast<const int2*>(edges + base + i * 2);
        int2 v2 = *reinterpret_cast<const int2*>(vertex + base + i * 2);
        atomicAdd(&cE[e2.x >> 9], 1); atomicAdd(&cE[e2.y >> 9], 1);
        atomicAdd(&cV[v2.x >> 9], 1); atomicAdd(&cV[v2.y >> 9], 1);
    }
    __syncthreads();
    // reserve contiguous runs
    for (int i = t; i < NBE; i += 256) {
        int c = cE[i];
        bE[i] = c ? atomicAdd(&gEcur[i], c) : 0;
        cE[i] = 0;
    }
    for (int i = t; i < NBV; i += 256) {
        int c = cV[i];
        bV[i] = c ? atomicAdd(&gVcur[i], c) : 0;
        cV[i] = 0;
    }
    __syncthreads();
    // pass 2: place packed payloads (re-read L2-hot; cached stores -> L2 coalesces lines)
    for (int i = t; i < CH2 / 2; i += 256) {
        int2 e2 = *reinterpret_cast<const int2*>(edges + base + i * 2);
        int2 v2 = *reinterpret_cast<const int2*>(vertex + base + i * 2);
        int pe0 = bE[e2.x >> 9] + atomicAdd(&cE[e2.x >> 9], 1);
        ebuckP[pe0] = ((unsigned)(e2.x & 511) << 17) | (unsigned)v2.x;
        int pe1 = bE[e2.y >> 9] + atomicAdd(&cE[e2.y >> 9], 1);
        ebuckP[pe1] = ((unsigned)(e2.y & 511) << 17) | (unsigned)v2.y;
        int pv0 = bV[v2.x >> 9] + atomicAdd(&cV[v2.x >> 9], 1);
        vbuckP[pv0] = ((unsigned)(v2.x & 511) << 16) | (unsigned)e2.x;
        int pv1 = bV[v2.y >> 9] + atomicAdd(&cV[v2.y >> 9], 1);
        vbuckP[pv1] = ((unsigned)(v2.y & 511) << 16) | (unsigned)e2.y;
    }
}

// ------- K5: per bucket: LDS per-id hist + scan -> eoff/voff, then place ----
__global__ __launch_bounds__(256) void place_buckets2(const unsigned int* __restrict__ ebuckP,
                                                      const unsigned int* __restrict__ vbuckP,
                                                      const int* __restrict__ eBase,
                                                      const int* __restrict__ vBase,
                                                      int* __restrict__ eoff,
                                                      int* __restrict__ voff,
                                                      int* __restrict__ vlist,
                                                      int* __restrict__ elist) {
    __shared__ int cnt[EBK];
    __shared__ int wsum[4];
    const int t = threadIdx.x;
    int b = blockIdx.x;
    const unsigned int* buck; int id0, nid, start, end; int* off; int* lst;
    int sh_amt; unsigned msk;
    if (b < NBE) {
        buck = ebuckP; id0 = b * EBK; nid = min(EBK, NE - id0);
        start = eBase[b]; end = eBase[b + 1]; off = eoff; lst = vlist;
        sh_amt = 17; msk = 0x1FFFFu;
    } else {
        b -= NBE;
        buck = vbuckP; id0 = b * VBK; nid = min(VBK, NN - id0);
        start = vBase[b]; end = vBase[b + 1]; off = voff; lst = elist;
        sh_amt = 16; msk = 0xFFFFu;
    }
    for (int i = t; i < nid; i += 256) cnt[i] = 0;
    __syncthreads();
    // pass 1: per-id histogram of this bucket's run
    for (int i = start + t; i < end; i += 256)
        atomicAdd(&cnt[buck[i] >> sh_amt], 1);
    __syncthreads();
    int c0 = (2 * t     < nid) ? cnt[2 * t]     : 0;
    int c1 = (2 * t + 1 < nid) ? cnt[2 * t + 1] : 0;
    int s = c0 + c1;
    int inc = s;
    #pragma unroll
    for (int d = 1; d < 64; d <<= 1) {
        int x = __shfl_up(inc, d, 64);
        if ((t & 63) >= d) inc += x;
    }
    if ((t & 63) == 63) wsum[t >> 6] = inc;
    __syncthreads();
    int wid = t >> 6, wbase = 0;
    #pragma unroll
    for (int w = 0; w < 3; ++w) if (w < wid) wbase += wsum[w];
    int excl = start + wbase + (inc - s);
    if (2 * t     < nid) off[id0 + 2 * t]     = excl;
    if (2 * t + 1 < nid) off[id0 + 2 * t + 1] = excl + c0;
    __syncthreads();
    if (2 * t     < nid) cnt[2 * t]     = excl;
    if (2 * t + 1 < nid) cnt[2 * t + 1] = excl + c0;
    __syncthreads();
    // pass 2: place payloads at final CSR slots
    for (int i = start + t; i < end; i += 256) {
        unsigned p = buck[i];
        lst[atomicAdd(&cnt[p >> sh_amt], 1)] = (int)(p & msk);
    }
}

// ---------------- K6: Xe[e] = mean of Xp16 rows; also Xe16 ----------------
__global__ __launch_bounds__(256) void edge_gather(const ushort* __restrict__ Xp16,
                                                   const int* __restrict__ eoff,
                                                   const int* __restrict__ vlist,
                                                   float* __restrict__ Xe,
                                                   ushort* __restrict__ Xe16) {
    int e = blockIdx.x * 8 + (threadIdx.x >> 5);
    if (e >= NE) return;
    int lane = threadIdx.x & 31;
    int start = eoff[e], end = eoff[e + 1];
    float ax = 0.f, ay = 0.f, az = 0.f, aw = 0.f;
    int j = start;
    for (; j + 7 < end; j += 8) {
        int v0 = vlist[j],     v1 = vlist[j + 1], v2 = vlist[j + 2], v3 = vlist[j + 3];
        int v4 = vlist[j + 4], v5 = vlist[j + 5], v6 = vlist[j + 6], v7 = vlist[j + 7];
        u32x2 u0 = ldg_u2(Xp16 + (size_t)v0 * DD + lane * 4);
        u32x2 u1 = ldg_u2(Xp16 + (size_t)v1 * DD + lane * 4);
        u32x2 u2 = ldg_u2(Xp16 + (size_t)v2 * DD + lane * 4);
        u32x2 u3 = ldg_u2(Xp16 + (size_t)v3 * DD + lane * 4);
        u32x2 u4 = ldg_u2(Xp16 + (size_t)v4 * DD + lane * 4);
        u32x2 u5 = ldg_u2(Xp16 + (size_t)v5 * DD + lane * 4);
        u32x2 u6 = ldg_u2(Xp16 + (size_t)v6 * DD + lane * 4);
        u32x2 u7 = ldg_u2(Xp16 + (size_t)v7 * DD + lane * 4);
        accP(u0, ax, ay, az, aw); accP(u1, ax, ay, az, aw);
        accP(u2, ax, ay, az, aw); accP(u3, ax, ay, az, aw);
        accP(u4, ax, ay, az, aw); accP(u5, ax, ay, az, aw);
        accP(u6, ax, ay, az, aw); accP(u7, ax, ay, az, aw);
    }
    for (; j < end; ++j) {
        u32x2 u = ldg_u2(Xp16 + (size_t)vlist[j] * DD + lane * 4);
        accP(u, ax, ay, az, aw);
    }
    float inv = 1.0f / fmaxf((float)(end - start), 1.0f);
    f32x4 o; o[0] = ax * inv; o[1] = ay * inv; o[2] = az * inv; o[3] = aw * inv;
    __builtin_nontemporal_store(o, reinterpret_cast<f32x4*>(Xe + (size_t)e * DD + lane * 4));
    ushort4 h;
    h.x = f2bf(o[0]); h.y = f2bf(o[1]); h.z = f2bf(o[2]); h.w = f2bf(o[3]);
    *reinterpret_cast<ushort4*>(Xe16 + (size_t)e * DD + lane * 4) = h;   // re-read by K7: cached
}

// -------- K7: Xv = sum Xe16 rows; out = normalize((1+eps)*Xp + Xv) --------
__global__ __launch_bounds__(256) void vertex_gather_out(const ushort* __restrict__ Xp16,
                                                         const ushort* __restrict__ Xe16,
                                                         const int* __restrict__ voff,
                                                         const int* __restrict__ elist,
                                                         const float* __restrict__ eps,
                                                         float* __restrict__ Out) {
    int v = blockIdx.x * 8 + (threadIdx.x >> 5);
    if (v >= NN) return;
    int lane = threadIdx.x & 31;
    int start = voff[v], end = voff[v + 1];
    float ax = 0.f, ay = 0.f, az = 0.f, aw = 0.f;
    int j = start;
    for (; j + 7 < end; j += 8) {
        int e0 = elist[j],     e1 = elist[j + 1], e2 = elist[j + 2], e3 = elist[j + 3];
        int e4 = elist[j + 4], e5 = elist[j + 5], e6 = elist[j + 6], e7 = elist[j + 7];
        u32x2 u0 = ldg_u2(Xe16 + (size_t)e0 * DD + lane * 4);
        u32x2 u1 = ldg_u2(Xe16 + (size_t)e1 * DD + lane * 4);
        u32x2 u2 = ldg_u2(Xe16 + (size_t)e2 * DD + lane * 4);
        u32x2 u3 = ldg_u2(Xe16 + (size_t)e3 * DD + lane * 4);
        u32x2 u4 = ldg_u2(Xe16 + (size_t)e4 * DD + lane * 4);
        u32x2 u5 = ldg_u2(Xe16 + (size_t)e5 * DD + lane * 4);
        u32x2 u6 = ldg_u2(Xe16 + (size_t)e6 * DD + lane * 4);
        u32x2 u7 = ldg_u2(Xe16 + (size_t)e7 * DD + lane * 4);
        accP(u0, ax, ay, az, aw); accP(u1, ax, ay, az, aw);
        accP(u2, ax, ay, az, aw); accP(u3, ax, ay, az, aw);
        accP(u4, ax, ay, az, aw); accP(u5, ax, ay, az, aw);
        accP(u6, ax, ay, az, aw); accP(u7, ax, ay, az, aw);
    }
    for (; j < end; ++j) {
        u32x2 u = ldg_u2(Xe16 + (size_t)elist[j] * DD + lane * 4);
        accP(u, ax, ay, az, aw);
    }
    float g = 1.0f + eps[0];
    u32x2 xp = __builtin_nontemporal_load(
        reinterpret_cast<const u32x2*>(Xp16 + (size_t)v * DD + lane * 4));  // sequential, read-once
    f32x4 o;
    o[0] = fmaf(g, __uint_as_float(xp.x << 16),         ax);
    o[1] = fmaf(g, __uint_as_float(xp.x & 0xffff0000u), ay);
    o[2] = fmaf(g, __uint_as_float(xp.y << 16),         az);
    o[3] = fmaf(g, __uint_as_float(xp.y & 0xffff0000u), aw);
    float ss = o[0] * o[0] + o[1] * o[1] + o[2] * o[2] + o[3] * o[3];
    #pragma unroll
    for (int off = 1; off < 32; off <<= 1) ss += __shfl_xor(ss, off, 64);
    float inv = 1.0f / fmaxf(sqrtf(ss), 1e-12f);
    o[0] *= inv; o[1] *= inv; o[2] *= inv; o[3] *= inv;
    __builtin_nontemporal_store(o, reinterpret_cast<f32x4*>(Out + (size_t)v * DD + lane * 4));
}

extern "C" void kernel_launch(void* const* d_in, const int* in_sizes, int n_in,
                              void* d_out, int out_size, void* d_ws, size_t ws_size,
                              hipStream_t stream) {
    const float* X      = (const float*)d_in[0];
    const float* W      = (const float*)d_in[1];
    const float* eps    = (const float*)d_in[2];
    const int*   vertex = (const int*)d_in[3];
    const int*   edges  = (const int*)d_in[4];

    float* out = (float*)d_out;                 // [N,D] — scratch for buckets until K7
    float* Xe  = out + (size_t)NN * DD;         // [E,D]

    // packed bucket arrays live in the 'out' region (dead until vertex_gather_out)
    unsigned int* ebuckP = (unsigned int*)out;  // NNZ ints = 6.4 MB
    unsigned int* vbuckP = ebuckP + NNZP;       // NNZ ints = 6.4 MB (total 12.8 <= 51.2)

    // workspace layout (~52 MB)
    ushort* Xp16 = (ushort*)d_ws;                        // N*D bf16
    ushort* Xe16 = Xp16 + (size_t)NN * DD;               // E*D bf16
    ushort* Wt16 = Xe16 + (size_t)NE * DD;               // D*D bf16
    int*    eoff = (int*)(Wt16 + DD * DD);               // E+1
    int*    voff = eoff + NE + 1;                        // N+1
    int*    vlist = voff + NN + 1;                       // NNZ
    int*    elist = vlist + NNZP;                        // NNZ
    int*    gEcnt = elist + NNZP;                        // NBE   (contiguous with gVcnt)
    int*    gVcnt = gEcnt + NBE;                         // NBV
    int*    gEcur = gVcnt + NBV;                         // NBE
    int*    gVcur = gEcur + NBE;                         // NBV
    int*    eBase = gVcur + NBV;                         // NBE+1
    int*    vBase = eBase + NBE + 1;                     // NBV+1

    hipMemsetAsync(gEcnt, 0, (size_t)NBT * sizeof(int), stream);

    hist_convert<<<NCHB + 64, 256, 0, stream>>>(vertex, edges, gEcnt, gVcnt, W, Wt16);
    gemm_mfma<<<(NN / 16 + 7) / 8, 256, 0, stream>>>(X, Wt16, Xp16);
    bucket_scan<<<1, 512, 0, stream>>>(gEcnt, eBase, vBase, gEcur, gVcur, eoff, voff);
    bucket_scatter2<<<NSB, 256, 0, stream>>>(vertex, edges, gEcur, gVcur, ebuckP, vbuckP);
    place_buckets2<<<NBT, 256, 0, stream>>>(ebuckP, vbuckP, eBase, vBase, eoff, voff, vlist, elist);
    edge_gather<<<NE / 8, 256, 0, stream>>>(Xp16, eoff, vlist, Xe, Xe16);
    vertex_gather_out<<<NN / 8, 256, 0, stream>>>(Xp16, Xe16, voff, elist, eps, out);
}

// Round 11
// 214.376 us; speedup vs baseline: 1.5946x; 1.1774x over previous
//
#include <hip/hip_runtime.h>
#include <hip/hip_bf16.h>

#define NN   100000
#define NE   50000
#define NNZP 1600000
#define DD   128

#define EBK  512
#define NBE  ((NE + EBK - 1) / EBK)             // 98
#define VBK  512
#define NBV  ((NN + VBK - 1) / VBK)             // 196
#define NBT  (NBE + NBV)                        // 294
#define CH2  3200                               // pairs per scatter block
#define NSB  500                                // 500 * 3200 == NNZP

typedef __attribute__((ext_vector_type(8))) short bf16x8;
typedef __attribute__((ext_vector_type(4))) float f32x4;
typedef __attribute__((ext_vector_type(2))) unsigned int u32x2;

__device__ __forceinline__ ushort f2bf(float f) {
    __hip_bfloat16 h = __float2bfloat16(f);
    return *reinterpret_cast<ushort*>(&h);
}
__device__ __forceinline__ void accP(u32x2 u, float& ax, float& ay, float& az, float& aw) {
    ax += __uint_as_float(u.x << 16);
    ay += __uint_as_float(u.x & 0xffff0000u);
    az += __uint_as_float(u.y << 16);
    aw += __uint_as_float(u.y & 0xffff0000u);
}
__device__ __forceinline__ u32x2 ldg_u2(const ushort* p) {
    return *reinterpret_cast<const u32x2*>(p);
}

// ------- K1: per-(bucket,block) counts, no global atomics; + Wt convert tail -------
__global__ __launch_bounds__(256) void scatter_count(const int* __restrict__ vertex,
                                                     const int* __restrict__ edges,
                                                     int* __restrict__ blkCnt,
                                                     const float* __restrict__ W,
                                                     ushort* __restrict__ Wt) {
    __shared__ int c[NBT];
    const int t = threadIdx.x;
    if (blockIdx.x >= NSB) {        // tail: Wt16[n][k] = bf16(W[k][n])
        int i = (blockIdx.x - NSB) * 256 + t;
        if (i < DD * DD) { int k = i >> 7, n = i & 127; Wt[n * DD + k] = f2bf(W[i]); }
        return;
    }
    for (int i = t; i < NBT; i += 256) c[i] = 0;
    __syncthreads();
    const int base = blockIdx.x * CH2;
    for (int i = t; i < CH2 / 4; i += 256) {
        int4 e4 = *reinterpret_cast<const int4*>(edges + base + i * 4);
        int4 v4 = *reinterpret_cast<const int4*>(vertex + base + i * 4);
        atomicAdd(&c[e4.x >> 9], 1); atomicAdd(&c[e4.y >> 9], 1);
        atomicAdd(&c[e4.z >> 9], 1); atomicAdd(&c[e4.w >> 9], 1);
        atomicAdd(&c[NBE + (v4.x >> 9)], 1); atomicAdd(&c[NBE + (v4.y >> 9)], 1);
        atomicAdd(&c[NBE + (v4.z >> 9)], 1); atomicAdd(&c[NBE + (v4.w >> 9)], 1);
    }
    __syncthreads();
    for (int i = t; i < NBT; i += 256) blkCnt[i * NSB + blockIdx.x] = c[i];
}

// ------- K2: per-bucket scan of 500 block counts -> relative offsets; total -> gCnt ----
__global__ __launch_bounds__(256) void blk_scan(int* __restrict__ blkCnt,
                                                int* __restrict__ gCnt) {
    __shared__ int wsum[4];
    const int t = threadIdx.x;
    int* p = blkCnt + blockIdx.x * NSB;
    int c0 = (2 * t     < NSB) ? p[2 * t]     : 0;
    int c1 = (2 * t + 1 < NSB) ? p[2 * t + 1] : 0;
    int s = c0 + c1;
    int inc = s;
    #pragma unroll
    for (int d = 1; d < 64; d <<= 1) {
        int x = __shfl_up(inc, d, 64);
        if ((t & 63) >= d) inc += x;
    }
    if ((t & 63) == 63) wsum[t >> 6] = inc;
    __syncthreads();
    int wid = t >> 6, wbase = 0;
    #pragma unroll
    for (int w = 0; w < 3; ++w) if (w < wid) wbase += wsum[w];
    int excl = wbase + inc - s;
    if (2 * t     < NSB) p[2 * t]     = excl;
    if (2 * t + 1 < NSB) p[2 * t + 1] = excl + c0;
    if (t == 255) gCnt[blockIdx.x] = wbase + inc;   // bucket total
}

// ------- K3: scan 294 bucket totals -> bases; fixed tails -------
__global__ __launch_bounds__(512) void bucket_scan(const int* __restrict__ gCnt,
                                                   int* __restrict__ eBase,
                                                   int* __restrict__ vBase,
                                                   int* __restrict__ eoff,
                                                   int* __restrict__ voff) {
    __shared__ int sh[512];
    int t = threadIdx.x;
    int v = (t < NBT) ? gCnt[t] : 0;
    sh[t] = v;
    __syncthreads();
    for (int d = 1; d < 512; d <<= 1) {
        int x = (t >= d) ? sh[t - d] : 0;
        __syncthreads();
        sh[t] += x;
        __syncthreads();
    }
    int excl = sh[t] - v;     // exclusive scan; edge buckets sum to NNZP
    if (t < NBE)      eBase[t] = excl;
    else if (t < NBT) vBase[t - NBE] = excl - NNZP;
    if (t == 0) { eBase[NBE] = NNZP; vBase[NBV] = NNZP; eoff[NE] = NNZP; voff[NN] = NNZP; }
}

// ------- K4: placement with precomputed deterministic cursors (LDS atomics only) ------
// ebuckP[i] = (e&511)<<17 | v ; vbuckP[i] = (v&511)<<16 | e
__global__ __launch_bounds__(256) void scatter_place(const int* __restrict__ vertex,
                                                     const int* __restrict__ edges,
                                                     const int* __restrict__ blkCnt,
                                                     const int* __restrict__ eBase,
                                                     const int* __restrict__ vBase,
                                                     unsigned int* __restrict__ ebuckP,
                                                     unsigned int* __restrict__ vbuckP) {
    __shared__ int cur[NBT];
    const int t = threadIdx.x;
    const int base = blockIdx.x * CH2;
    for (int i = t; i < NBT; i += 256) {
        int rel = blkCnt[i * NSB + blockIdx.x];
        cur[i] = ((i < NBE) ? eBase[i] : vBase[i - NBE]) + rel;
    }
    __syncthreads();
    for (int i = t; i < CH2 / 2; i += 256) {
        int2 e2 = *reinterpret_cast<const int2*>(edges + base + i * 2);
        int2 v2 = *reinterpret_cast<const int2*>(vertex + base + i * 2);
        int pe0 = atomicAdd(&cur[e2.x >> 9], 1);
        ebuckP[pe0] = ((unsigned)(e2.x & 511) << 17) | (unsigned)v2.x;
        int pe1 = atomicAdd(&cur[e2.y >> 9], 1);
        ebuckP[pe1] = ((unsigned)(e2.y & 511) << 17) | (unsigned)v2.y;
        int pv0 = atomicAdd(&cur[NBE + (v2.x >> 9)], 1);
        vbuckP[pv0] = ((unsigned)(v2.x & 511) << 16) | (unsigned)e2.x;
        int pv1 = atomicAdd(&cur[NBE + (v2.y >> 9)], 1);
        vbuckP[pv1] = ((unsigned)(v2.y & 511) << 16) | (unsigned)e2.y;
    }
}

// ---------------- K5: Xp16 = bf16( X @ W ) via MFMA (2 rowTiles/wave) ----------------
__global__ __launch_bounds__(256) void gemm_mfma(const float* __restrict__ X,
                                                 const ushort* __restrict__ Wt,
                                                 ushort* __restrict__ Xp16) {
    __shared__ char WtL[DD * DD * 2];   // 32 KB, XOR-swizzled 16B chunks
    for (int c = threadIdx.x; c < 2048; c += 256) {
        int n = c >> 4, kc = c & 15;
        int dst = (n * 256 + kc * 16) ^ ((n & 7) << 4);
        *reinterpret_cast<int4*>(WtL + dst) = reinterpret_cast<const int4*>(Wt)[c];
    }
    __syncthreads();
    int wave = threadIdx.x >> 6;
    int lane = threadIdx.x & 63;
    int r = lane & 15, half = lane >> 4;
    #pragma unroll
    for (int rt = 0; rt < 2; ++rt) {
        int rowTile = blockIdx.x * 8 + wave * 2 + rt;
        if (rowTile >= NN / 16) break;
        const float* xrow = X + (size_t)(rowTile * 16 + r) * DD;
        f32x4 acc[8];
        #pragma unroll
        for (int nt = 0; nt < 8; ++nt) acc[nt] = (f32x4)(0.f);
        #pragma unroll
        for (int kk = 0; kk < DD; kk += 32) {
            int kbase = kk + half * 8;
            float4 xa = *reinterpret_cast<const float4*>(xrow + kbase);
            float4 xb = *reinterpret_cast<const float4*>(xrow + kbase + 4);
            bf16x8 a;
            a[0] = (short)f2bf(xa.x); a[1] = (short)f2bf(xa.y);
            a[2] = (short)f2bf(xa.z); a[3] = (short)f2bf(xa.w);
            a[4] = (short)f2bf(xb.x); a[5] = (short)f2bf(xb.y);
            a[6] = (short)f2bf(xb.z); a[7] = (short)f2bf(xb.w);
            #pragma unroll
            for (int nt = 0; nt < 8; ++nt) {
                int n = nt * 16 + r;
                int off = (n * 256 + kbase * 2) ^ ((n & 7) << 4);
                bf16x8 b = *reinterpret_cast<const bf16x8*>(WtL + off);
                acc[nt] = __builtin_amdgcn_mfma_f32_16x16x32_bf16(a, b, acc[nt], 0, 0, 0);
            }
        }
        int row0 = rowTile * 16 + half * 4;   // C/D: col=lane&15, row=(lane>>4)*4+q
        #pragma unroll
        for (int nt = 0; nt < 8; ++nt)
            #pragma unroll
            for (int q = 0; q < 4; ++q)
                Xp16[(size_t)(row0 + q) * DD + nt * 16 + r] = f2bf(acc[nt][q]);
    }
}

// ------- K6: per bucket: LDS per-id hist + scan -> eoff/voff, then place ----
__global__ __launch_bounds__(256) void place_buckets2(const unsigned int* __restrict__ ebuckP,
                                                      const unsigned int* __restrict__ vbuckP,
                                                      const int* __restrict__ eBase,
                                                      const int* __restrict__ vBase,
                                                      int* __restrict__ eoff,
                                                      int* __restrict__ voff,
                                                      int* __restrict__ vlist,
                                                      int* __restrict__ elist) {
    __shared__ int cnt[EBK];
    __shared__ int wsum[4];
    const int t = threadIdx.x;
    int b = blockIdx.x;
    const unsigned int* buck; int id0, nid, start, end; int* off; int* lst;
    int sh_amt; unsigned msk;
    if (b < NBE) {
        buck = ebuckP; id0 = b * EBK; nid = min(EBK, NE - id0);
        start = eBase[b]; end = eBase[b + 1]; off = eoff; lst = vlist;
        sh_amt = 17; msk = 0x1FFFFu;
    } else {
        b -= NBE;
        buck = vbuckP; id0 = b * VBK; nid = min(VBK, NN - id0);
        start = vBase[b]; end = vBase[b + 1]; off = voff; lst = elist;
        sh_amt = 16; msk = 0xFFFFu;
    }
    for (int i = t; i < nid; i += 256) cnt[i] = 0;
    __syncthreads();
    for (int i = start + t; i < end; i += 256)
        atomicAdd(&cnt[buck[i] >> sh_amt], 1);
    __syncthreads();
    int c0 = (2 * t     < nid) ? cnt[2 * t]     : 0;
    int c1 = (2 * t + 1 < nid) ? cnt[2 * t + 1] : 0;
    int s = c0 + c1;
    int inc = s;
    #pragma unroll
    for (int d = 1; d < 64; d <<= 1) {
        int x = __shfl_up(inc, d, 64);
        if ((t & 63) >= d) inc += x;
    }
    if ((t & 63) == 63) wsum[t >> 6] = inc;
    __syncthreads();
    int wid = t >> 6, wbase = 0;
    #pragma unroll
    for (int w = 0; w < 3; ++w) if (w < wid) wbase += wsum[w];
    int excl = start + wbase + (inc - s);
    if (2 * t     < nid) off[id0 + 2 * t]     = excl;
    if (2 * t + 1 < nid) off[id0 + 2 * t + 1] = excl + c0;
    __syncthreads();
    if (2 * t     < nid) cnt[2 * t]     = excl;
    if (2 * t + 1 < nid) cnt[2 * t + 1] = excl + c0;
    __syncthreads();
    for (int i = start + t; i < end; i += 256) {
        unsigned p = buck[i];
        lst[atomicAdd(&cnt[p >> sh_amt], 1)] = (int)(p & msk);
    }
}

// ---------------- K7: Xe[e] = mean of Xp16 rows; also Xe16 ----------------
__global__ __launch_bounds__(256) void edge_gather(const ushort* __restrict__ Xp16,
                                                   const int* __restrict__ eoff,
                                                   const int* __restrict__ vlist,
                                                   float* __restrict__ Xe,
                                                   ushort* __restrict__ Xe16) {
    int e = blockIdx.x * 8 + (threadIdx.x >> 5);
    if (e >= NE) return;
    int lane = threadIdx.x & 31;
    int start = eoff[e], end = eoff[e + 1];
    float ax = 0.f, ay = 0.f, az = 0.f, aw = 0.f;
    int j = start;
    for (; j + 15 < end; j += 16) {
        u32x2 u[16];
        #pragma unroll
        for (int k = 0; k < 16; ++k)
            u[k] = ldg_u2(Xp16 + (size_t)vlist[j + k] * DD + lane * 4);
        #pragma unroll
        for (int k = 0; k < 16; ++k) accP(u[k], ax, ay, az, aw);
    }
    for (; j + 3 < end; j += 4) {
        u32x2 u[4];
        #pragma unroll
        for (int k = 0; k < 4; ++k)
            u[k] = ldg_u2(Xp16 + (size_t)vlist[j + k] * DD + lane * 4);
        #pragma unroll
        for (int k = 0; k < 4; ++k) accP(u[k], ax, ay, az, aw);
    }
    for (; j < end; ++j) {
        u32x2 u = ldg_u2(Xp16 + (size_t)vlist[j] * DD + lane * 4);
        accP(u, ax, ay, az, aw);
    }
    float inv = 1.0f / fmaxf((float)(end - start), 1.0f);
    f32x4 o; o[0] = ax * inv; o[1] = ay * inv; o[2] = az * inv; o[3] = aw * inv;
    __builtin_nontemporal_store(o, reinterpret_cast<f32x4*>(Xe + (size_t)e * DD + lane * 4));
    ushort4 h;
    h.x = f2bf(o[0]); h.y = f2bf(o[1]); h.z = f2bf(o[2]); h.w = f2bf(o[3]);
    *reinterpret_cast<ushort4*>(Xe16 + (size_t)e * DD + lane * 4) = h;
}

// -------- K8: Xv = sum Xe16 rows; out = normalize((1+eps)*Xp + Xv) --------
__global__ __launch_bounds__(256) void vertex_gather_out(const ushort* __restrict__ Xp16,
                                                         const ushort* __restrict__ Xe16,
                                                         const int* __restrict__ voff,
                                                         const int* __restrict__ elist,
                                                         const float* __restrict__ eps,
                                                         float* __restrict__ Out) {
    int v = blockIdx.x * 8 + (threadIdx.x >> 5);
    if (v >= NN) return;
    int lane = threadIdx.x & 31;
    int start = voff[v], end = voff[v + 1];
    float ax = 0.f, ay = 0.f, az = 0.f, aw = 0.f;
    int j = start;
    for (; j + 15 < end; j += 16) {
        u32x2 u[16];
        #pragma unroll
        for (int k = 0; k < 16; ++k)
            u[k] = ldg_u2(Xe16 + (size_t)elist[j + k] * DD + lane * 4);
        #pragma unroll
        for (int k = 0; k < 16; ++k) accP(u[k], ax, ay, az, aw);
    }
    for (; j + 3 < end; j += 4) {
        u32x2 u[4];
        #pragma unroll
        for (int k = 0; k < 4; ++k)
            u[k] = ldg_u2(Xe16 + (size_t)elist[j + k] * DD + lane * 4);
        #pragma unroll
        for (int k = 0; k < 4; ++k) accP(u[k], ax, ay, az, aw);
    }
    for (; j < end; ++j) {
        u32x2 u = ldg_u2(Xe16 + (size_t)elist[j] * DD + lane * 4);
        accP(u, ax, ay, az, aw);
    }
    float g = 1.0f + eps[0];
    u32x2 xp = __builtin_nontemporal_load(
        reinterpret_cast<const u32x2*>(Xp16 + (size_t)v * DD + lane * 4));
    f32x4 o;
    o[0] = fmaf(g, __uint_as_float(xp.x << 16),         ax);
    o[1] = fmaf(g, __uint_as_float(xp.x & 0xffff0000u), ay);
    o[2] = fmaf(g, __uint_as_float(xp.y << 16),         az);
    o[3] = fmaf(g, __uint_as_float(xp.y & 0xffff0000u), aw);
    float ss = o[0] * o[0] + o[1] * o[1] + o[2] * o[2] + o[3] * o[3];
    #pragma unroll
    for (int off = 1; off < 32; off <<= 1) ss += __shfl_xor(ss, off, 64);
    float inv = 1.0f / fmaxf(sqrtf(ss), 1e-12f);
    o[0] *= inv; o[1] *= inv; o[2] *= inv; o[3] *= inv;
    __builtin_nontemporal_store(o, reinterpret_cast<f32x4*>(Out + (size_t)v * DD + lane * 4));
}

extern "C" void kernel_launch(void* const* d_in, const int* in_sizes, int n_in,
                              void* d_out, int out_size, void* d_ws, size_t ws_size,
                              hipStream_t stream) {
    const float* X      = (const float*)d_in[0];
    const float* W      = (const float*)d_in[1];
    const float* eps    = (const float*)d_in[2];
    const int*   vertex = (const int*)d_in[3];
    const int*   edges  = (const int*)d_in[4];

    float* out = (float*)d_out;                 // [N,D] — scratch for buckets until K8
    float* Xe  = out + (size_t)NN * DD;         // [E,D]

    // packed bucket arrays live in the 'out' region (dead until vertex_gather_out)
    unsigned int* ebuckP = (unsigned int*)out;  // NNZ ints = 6.4 MB
    unsigned int* vbuckP = ebuckP + NNZP;       // NNZ ints = 6.4 MB (total 12.8 <= 51.2)

    // workspace layout (~52.5 MB)
    ushort* Xp16 = (ushort*)d_ws;                        // N*D bf16
    ushort* Xe16 = Xp16 + (size_t)NN * DD;               // E*D bf16
    ushort* Wt16 = Xe16 + (size_t)NE * DD;               // D*D bf16
    int*    eoff = (int*)(Wt16 + DD * DD);               // E+1
    int*    voff = eoff + NE + 1;                        // N+1
    int*    vlist = voff + NN + 1;                       // NNZ
    int*    elist = vlist + NNZP;                        // NNZ
    int*    gCnt  = elist + NNZP;                        // NBT
    int*    eBase = gCnt + NBT;                          // NBE+1
    int*    vBase = eBase + NBE + 1;                     // NBV+1
    int*    blkCnt = vBase + NBV + 1;                    // NBT*NSB = 147000

    scatter_count<<<NSB + 64, 256, 0, stream>>>(vertex, edges, blkCnt, W, Wt16);
    gemm_mfma<<<(NN / 16 + 7) / 8, 256, 0, stream>>>(X, Wt16, Xp16);
    blk_scan<<<NBT, 256, 0, stream>>>(blkCnt, gCnt);
    bucket_scan<<<1, 512, 0, stream>>>(gCnt, eBase, vBase, eoff, voff);
    scatter_place<<<NSB, 256, 0, stream>>>(vertex, edges, blkCnt, eBase, vBase, ebuckP, vbuckP);
    place_buckets2<<<NBT, 256, 0, stream>>>(ebuckP, vbuckP, eBase, vBase, eoff, voff, vlist, elist);
    edge_gather<<<NE / 8, 256, 0, stream>>>(Xp16, eoff, vlist, Xe, Xe16);
    vertex_gather_out<<<NN / 8, 256, 0, stream>>>(Xp16, Xe16, voff, elist, eps, out);
}

// Round 12
// 213.492 us; speedup vs baseline: 1.6012x; 1.0041x over previous
//
#include <hip/hip_runtime.h>
#include <hip/hip_bf16.h>

#define NN   100000
#define NE   50000
#define NNZP 1600000
#define DD   128

#define EBK  512
#define NBE  ((NE + EBK - 1) / EBK)             // 98
#define VBK  512
#define NBV  ((NN + VBK - 1) / VBK)             // 196
#define NBT  (NBE + NBV)                        // 294
#define CH2  3200                               // pairs per scatter block
#define NSB  500                                // 500 * 3200 == NNZP

typedef __attribute__((ext_vector_type(8))) short bf16x8;
typedef __attribute__((ext_vector_type(4))) float f32x4;
typedef __attribute__((ext_vector_type(2))) unsigned int u32x2;

__device__ __forceinline__ ushort f2bf(float f) {
    __hip_bfloat16 h = __float2bfloat16(f);
    return *reinterpret_cast<ushort*>(&h);
}
__device__ __forceinline__ void accP(u32x2 u, float& ax, float& ay, float& az, float& aw) {
    ax += __uint_as_float(u.x << 16);
    ay += __uint_as_float(u.x & 0xffff0000u);
    az += __uint_as_float(u.y << 16);
    aw += __uint_as_float(u.y & 0xffff0000u);
}
__device__ __forceinline__ u32x2 ldg_u2(const ushort* p) {
    return *reinterpret_cast<const u32x2*>(p);
}

// ------- K1: per-(bucket,block) counts, no global atomics; + Wt convert tail -------
__global__ __launch_bounds__(256) void scatter_count(const int* __restrict__ vertex,
                                                     const int* __restrict__ edges,
                                                     int* __restrict__ blkCnt,
                                                     const float* __restrict__ W,
                                                     ushort* __restrict__ Wt) {
    __shared__ int c[NBT];
    const int t = threadIdx.x;
    if (blockIdx.x >= NSB) {        // tail: Wt16[n][k] = bf16(W[k][n])
        int i = (blockIdx.x - NSB) * 256 + t;
        if (i < DD * DD) { int k = i >> 7, n = i & 127; Wt[n * DD + k] = f2bf(W[i]); }
        return;
    }
    for (int i = t; i < NBT; i += 256) c[i] = 0;
    __syncthreads();
    const int base = blockIdx.x * CH2;
    for (int i = t; i < CH2 / 4; i += 256) {
        int4 e4 = *reinterpret_cast<const int4*>(edges + base + i * 4);
        int4 v4 = *reinterpret_cast<const int4*>(vertex + base + i * 4);
        atomicAdd(&c[e4.x >> 9], 1); atomicAdd(&c[e4.y >> 9], 1);
        atomicAdd(&c[e4.z >> 9], 1); atomicAdd(&c[e4.w >> 9], 1);
        atomicAdd(&c[NBE + (v4.x >> 9)], 1); atomicAdd(&c[NBE + (v4.y >> 9)], 1);
        atomicAdd(&c[NBE + (v4.z >> 9)], 1); atomicAdd(&c[NBE + (v4.w >> 9)], 1);
    }
    __syncthreads();
    for (int i = t; i < NBT; i += 256) blkCnt[i * NSB + blockIdx.x] = c[i];
}

// ------- K2: per-bucket scan of 500 block counts -> relative offsets; total -> gCnt ----
__global__ __launch_bounds__(256) void blk_scan(int* __restrict__ blkCnt,
                                                int* __restrict__ gCnt) {
    __shared__ int wsum[4];
    const int t = threadIdx.x;
    int* p = blkCnt + blockIdx.x * NSB;
    int c0 = (2 * t     < NSB) ? p[2 * t]     : 0;
    int c1 = (2 * t + 1 < NSB) ? p[2 * t + 1] : 0;
    int s = c0 + c1;
    int inc = s;
    #pragma unroll
    for (int d = 1; d < 64; d <<= 1) {
        int x = __shfl_up(inc, d, 64);
        if ((t & 63) >= d) inc += x;
    }
    if ((t & 63) == 63) wsum[t >> 6] = inc;
    __syncthreads();
    int wid = t >> 6, wbase = 0;
    #pragma unroll
    for (int w = 0; w < 3; ++w) if (w < wid) wbase += wsum[w];
    int excl = wbase + inc - s;
    if (2 * t     < NSB) p[2 * t]     = excl;
    if (2 * t + 1 < NSB) p[2 * t + 1] = excl + c0;
    if (t == 255) gCnt[blockIdx.x] = wbase + inc;   // bucket total
}

// ------- K3: scan 294 bucket totals -> bases; fixed tails -------
__global__ __launch_bounds__(512) void bucket_scan(const int* __restrict__ gCnt,
                                                   int* __restrict__ eBase,
                                                   int* __restrict__ vBase,
                                                   int* __restrict__ eoff,
                                                   int* __restrict__ voff) {
    __shared__ int sh[512];
    int t = threadIdx.x;
    int v = (t < NBT) ? gCnt[t] : 0;
    sh[t] = v;
    __syncthreads();
    for (int d = 1; d < 512; d <<= 1) {
        int x = (t >= d) ? sh[t - d] : 0;
        __syncthreads();
        sh[t] += x;
        __syncthreads();
    }
    int excl = sh[t] - v;     // exclusive scan; edge buckets sum to NNZP
    if (t < NBE)      eBase[t] = excl;
    else if (t < NBT) vBase[t - NBE] = excl - NNZP;
    if (t == 0) { eBase[NBE] = NNZP; vBase[NBV] = NNZP; eoff[NE] = NNZP; voff[NN] = NNZP; }
}

// ------- K4: placement with precomputed deterministic cursors (LDS atomics only) ------
// ebuckP[i] = (e&511)<<17 | v ; vbuckP[i] = (v&511)<<16 | e
__global__ __launch_bounds__(256) void scatter_place(const int* __restrict__ vertex,
                                                     const int* __restrict__ edges,
                                                     const int* __restrict__ blkCnt,
                                                     const int* __restrict__ eBase,
                                                     const int* __restrict__ vBase,
                                                     unsigned int* __restrict__ ebuckP,
                                                     unsigned int* __restrict__ vbuckP) {
    __shared__ int cur[NBT];
    const int t = threadIdx.x;
    const int base = blockIdx.x * CH2;
    for (int i = t; i < NBT; i += 256) {
        int rel = blkCnt[i * NSB + blockIdx.x];
        cur[i] = ((i < NBE) ? eBase[i] : vBase[i - NBE]) + rel;
    }
    __syncthreads();
    for (int i = t; i < CH2 / 2; i += 256) {
        int2 e2 = *reinterpret_cast<const int2*>(edges + base + i * 2);
        int2 v2 = *reinterpret_cast<const int2*>(vertex + base + i * 2);
        int pe0 = atomicAdd(&cur[e2.x >> 9], 1);
        ebuckP[pe0] = ((unsigned)(e2.x & 511) << 17) | (unsigned)v2.x;
        int pe1 = atomicAdd(&cur[e2.y >> 9], 1);
        ebuckP[pe1] = ((unsigned)(e2.y & 511) << 17) | (unsigned)v2.y;
        int pv0 = atomicAdd(&cur[NBE + (v2.x >> 9)], 1);
        vbuckP[pv0] = ((unsigned)(v2.x & 511) << 16) | (unsigned)e2.x;
        int pv1 = atomicAdd(&cur[NBE + (v2.y >> 9)], 1);
        vbuckP[pv1] = ((unsigned)(v2.y & 511) << 16) | (unsigned)e2.y;
    }
}

// ---------------- K5: Xp16 = bf16( X @ W ) via MFMA (2 rowTiles/wave) ----------------
__global__ __launch_bounds__(256) void gemm_mfma(const float* __restrict__ X,
                                                 const ushort* __restrict__ Wt,
                                                 ushort* __restrict__ Xp16) {
    __shared__ char WtL[DD * DD * 2];   // 32 KB, XOR-swizzled 16B chunks
    for (int c = threadIdx.x; c < 2048; c += 256) {
        int n = c >> 4, kc = c & 15;
        int dst = (n * 256 + kc * 16) ^ ((n & 7) << 4);
        *reinterpret_cast<int4*>(WtL + dst) = reinterpret_cast<const int4*>(Wt)[c];
    }
    __syncthreads();
    int wave = threadIdx.x >> 6;
    int lane = threadIdx.x & 63;
    int r = lane & 15, half = lane >> 4;
    #pragma unroll
    for (int rt = 0; rt < 2; ++rt) {
        int rowTile = blockIdx.x * 8 + wave * 2 + rt;
        if (rowTile >= NN / 16) break;
        const float* xrow = X + (size_t)(rowTile * 16 + r) * DD;
        f32x4 acc[8];
        #pragma unroll
        for (int nt = 0; nt < 8; ++nt) acc[nt] = (f32x4)(0.f);
        #pragma unroll
        for (int kk = 0; kk < DD; kk += 32) {
            int kbase = kk + half * 8;
            float4 xa = *reinterpret_cast<const float4*>(xrow + kbase);
            float4 xb = *reinterpret_cast<const float4*>(xrow + kbase + 4);
            bf16x8 a;
            a[0] = (short)f2bf(xa.x); a[1] = (short)f2bf(xa.y);
            a[2] = (short)f2bf(xa.z); a[3] = (short)f2bf(xa.w);
            a[4] = (short)f2bf(xb.x); a[5] = (short)f2bf(xb.y);
            a[6] = (short)f2bf(xb.z); a[7] = (short)f2bf(xb.w);
            #pragma unroll
            for (int nt = 0; nt < 8; ++nt) {
                int n = nt * 16 + r;
                int off = (n * 256 + kbase * 2) ^ ((n & 7) << 4);
                bf16x8 b = *reinterpret_cast<const bf16x8*>(WtL + off);
                acc[nt] = __builtin_amdgcn_mfma_f32_16x16x32_bf16(a, b, acc[nt], 0, 0, 0);
            }
        }
        int row0 = rowTile * 16 + half * 4;   // C/D: col=lane&15, row=(lane>>4)*4+q
        #pragma unroll
        for (int nt = 0; nt < 8; ++nt)
            #pragma unroll
            for (int q = 0; q < 4; ++q)
                Xp16[(size_t)(row0 + q) * DD + nt * 16 + r] = f2bf(acc[nt][q]);
    }
}

// ------- K6: per bucket: LDS per-id hist + scan -> eoff/voff, then place ----
__global__ __launch_bounds__(256) void place_buckets2(const unsigned int* __restrict__ ebuckP,
                                                      const unsigned int* __restrict__ vbuckP,
                                                      const int* __restrict__ eBase,
                                                      const int* __restrict__ vBase,
                                                      int* __restrict__ eoff,
                                                      int* __restrict__ voff,
                                                      int* __restrict__ vlist,
                                                      int* __restrict__ elist) {
    __shared__ int cnt[EBK];
    __shared__ int wsum[4];
    const int t = threadIdx.x;
    int b = blockIdx.x;
    const unsigned int* buck; int id0, nid, start, end; int* off; int* lst;
    int sh_amt; unsigned msk;
    if (b < NBE) {
        buck = ebuckP; id0 = b * EBK; nid = min(EBK, NE - id0);
        start = eBase[b]; end = eBase[b + 1]; off = eoff; lst = vlist;
        sh_amt = 17; msk = 0x1FFFFu;
    } else {
        b -= NBE;
        buck = vbuckP; id0 = b * VBK; nid = min(VBK, NN - id0);
        start = vBase[b]; end = vBase[b + 1]; off = voff; lst = elist;
        sh_amt = 16; msk = 0xFFFFu;
    }
    for (int i = t; i < nid; i += 256) cnt[i] = 0;
    __syncthreads();
    for (int i = start + t; i < end; i += 256)
        atomicAdd(&cnt[buck[i] >> sh_amt], 1);
    __syncthreads();
    int c0 = (2 * t     < nid) ? cnt[2 * t]     : 0;
    int c1 = (2 * t + 1 < nid) ? cnt[2 * t + 1] : 0;
    int s = c0 + c1;
    int inc = s;
    #pragma unroll
    for (int d = 1; d < 64; d <<= 1) {
        int x = __shfl_up(inc, d, 64);
        if ((t & 63) >= d) inc += x;
    }
    if ((t & 63) == 63) wsum[t >> 6] = inc;
    __syncthreads();
    int wid = t >> 6, wbase = 0;
    #pragma unroll
    for (int w = 0; w < 3; ++w) if (w < wid) wbase += wsum[w];
    int excl = start + wbase + (inc - s);
    if (2 * t     < nid) off[id0 + 2 * t]     = excl;
    if (2 * t + 1 < nid) off[id0 + 2 * t + 1] = excl + c0;
    __syncthreads();
    if (2 * t     < nid) cnt[2 * t]     = excl;
    if (2 * t + 1 < nid) cnt[2 * t + 1] = excl + c0;
    __syncthreads();
    for (int i = start + t; i < end; i += 256) {
        unsigned p = buck[i];
        lst[atomicAdd(&cnt[p >> sh_amt], 1)] = (int)(p & msk);
    }
}

// ---------------- K7: Xe[e] = mean of Xp16 rows; also Xe16 (8-deep, VGPR-lean) -------
__global__ __launch_bounds__(256) void edge_gather(const ushort* __restrict__ Xp16,
                                                   const int* __restrict__ eoff,
                                                   const int* __restrict__ vlist,
                                                   float* __restrict__ Xe,
                                                   ushort* __restrict__ Xe16) {
    int e = blockIdx.x * 8 + (threadIdx.x >> 5);
    if (e >= NE) return;
    int lane = threadIdx.x & 31;
    int start = eoff[e], end = eoff[e + 1];
    float ax = 0.f, ay = 0.f, az = 0.f, aw = 0.f;
    int j = start;
    for (; j + 7 < end; j += 8) {
        int v0 = vlist[j],     v1 = vlist[j + 1], v2 = vlist[j + 2], v3 = vlist[j + 3];
        int v4 = vlist[j + 4], v5 = vlist[j + 5], v6 = vlist[j + 6], v7 = vlist[j + 7];
        u32x2 u0 = ldg_u2(Xp16 + (size_t)v0 * DD + lane * 4);
        u32x2 u1 = ldg_u2(Xp16 + (size_t)v1 * DD + lane * 4);
        u32x2 u2 = ldg_u2(Xp16 + (size_t)v2 * DD + lane * 4);
        u32x2 u3 = ldg_u2(Xp16 + (size_t)v3 * DD + lane * 4);
        u32x2 u4 = ldg_u2(Xp16 + (size_t)v4 * DD + lane * 4);
        u32x2 u5 = ldg_u2(Xp16 + (size_t)v5 * DD + lane * 4);
        u32x2 u6 = ldg_u2(Xp16 + (size_t)v6 * DD + lane * 4);
        u32x2 u7 = ldg_u2(Xp16 + (size_t)v7 * DD + lane * 4);
        accP(u0, ax, ay, az, aw); accP(u1, ax, ay, az, aw);
        accP(u2, ax, ay, az, aw); accP(u3, ax, ay, az, aw);
        accP(u4, ax, ay, az, aw); accP(u5, ax, ay, az, aw);
        accP(u6, ax, ay, az, aw); accP(u7, ax, ay, az, aw);
    }
    for (; j < end; ++j) {
        u32x2 u = ldg_u2(Xp16 + (size_t)vlist[j] * DD + lane * 4);
        accP(u, ax, ay, az, aw);
    }
    float inv = 1.0f / fmaxf((float)(end - start), 1.0f);
    f32x4 o; o[0] = ax * inv; o[1] = ay * inv; o[2] = az * inv; o[3] = aw * inv;
    __builtin_nontemporal_store(o, reinterpret_cast<f32x4*>(Xe + (size_t)e * DD + lane * 4));
    ushort4 h;
    h.x = f2bf(o[0]); h.y = f2bf(o[1]); h.z = f2bf(o[2]); h.w = f2bf(o[3]);
    *reinterpret_cast<ushort4*>(Xe16 + (size_t)e * DD + lane * 4) = h;   // re-read by K8: cached
}

// -------- K8: Xv = sum Xe16 rows; out = normalize((1+eps)*Xp + Xv) (8-deep) --------
__global__ __launch_bounds__(256) void vertex_gather_out(const ushort* __restrict__ Xp16,
                                                         const ushort* __restrict__ Xe16,
                                                         const int* __restrict__ voff,
                                                         const int* __restrict__ elist,
                                                         const float* __restrict__ eps,
                                                         float* __restrict__ Out) {
    int v = blockIdx.x * 8 + (threadIdx.x >> 5);
    if (v >= NN) return;
    int lane = threadIdx.x & 31;
    int start = voff[v], end = voff[v + 1];
    float ax = 0.f, ay = 0.f, az = 0.f, aw = 0.f;
    int j = start;
    for (; j + 7 < end; j += 8) {
        int e0 = elist[j],     e1 = elist[j + 1], e2 = elist[j + 2], e3 = elist[j + 3];
        int e4 = elist[j + 4], e5 = elist[j + 5], e6 = elist[j + 6], e7 = elist[j + 7];
        u32x2 u0 = ldg_u2(Xe16 + (size_t)e0 * DD + lane * 4);
        u32x2 u1 = ldg_u2(Xe16 + (size_t)e1 * DD + lane * 4);
        u32x2 u2 = ldg_u2(Xe16 + (size_t)e2 * DD + lane * 4);
        u32x2 u3 = ldg_u2(Xe16 + (size_t)e3 * DD + lane * 4);
        u32x2 u4 = ldg_u2(Xe16 + (size_t)e4 * DD + lane * 4);
        u32x2 u5 = ldg_u2(Xe16 + (size_t)e5 * DD + lane * 4);
        u32x2 u6 = ldg_u2(Xe16 + (size_t)e6 * DD + lane * 4);
        u32x2 u7 = ldg_u2(Xe16 + (size_t)e7 * DD + lane * 4);
        accP(u0, ax, ay, az, aw); accP(u1, ax, ay, az, aw);
        accP(u2, ax, ay, az, aw); accP(u3, ax, ay, az, aw);
        accP(u4, ax, ay, az, aw); accP(u5, ax, ay, az, aw);
        accP(u6, ax, ay, az, aw); accP(u7, ax, ay, az, aw);
    }
    for (; j < end; ++j) {
        u32x2 u = ldg_u2(Xe16 + (size_t)elist[j] * DD + lane * 4);
        accP(u, ax, ay, az, aw);
    }
    float g = 1.0f + eps[0];
    u32x2 xp = __builtin_nontemporal_load(
        reinterpret_cast<const u32x2*>(Xp16 + (size_t)v * DD + lane * 4));  // sequential, read-once
    f32x4 o;
    o[0] = fmaf(g, __uint_as_float(xp.x << 16),         ax);
    o[1] = fmaf(g, __uint_as_float(xp.x & 0xffff0000u), ay);
    o[2] = fmaf(g, __uint_as_float(xp.y << 16),         az);
    o[3] = fmaf(g, __uint_as_float(xp.y & 0xffff0000u), aw);
    float ss = o[0] * o[0] + o[1] * o[1] + o[2] * o[2] + o[3] * o[3];
    #pragma unroll
    for (int off = 1; off < 32; off <<= 1) ss += __shfl_xor(ss, off, 64);
    float inv = 1.0f / fmaxf(sqrtf(ss), 1e-12f);
    o[0] *= inv; o[1] *= inv; o[2] *= inv; o[3] *= inv;
    __builtin_nontemporal_store(o, reinterpret_cast<f32x4*>(Out + (size_t)v * DD + lane * 4));
}

extern "C" void kernel_launch(void* const* d_in, const int* in_sizes, int n_in,
                              void* d_out, int out_size, void* d_ws, size_t ws_size,
                              hipStream_t stream) {
    const float* X      = (const float*)d_in[0];
    const float* W      = (const float*)d_in[1];
    const float* eps    = (const float*)d_in[2];
    const int*   vertex = (const int*)d_in[3];
    const int*   edges  = (const int*)d_in[4];

    float* out = (float*)d_out;                 // [N,D] — scratch for buckets until K8
    float* Xe  = out + (size_t)NN * DD;         // [E,D]

    // packed bucket arrays live in the 'out' region (dead until vertex_gather_out)
    unsigned int* ebuckP = (unsigned int*)out;  // NNZ ints = 6.4 MB
    unsigned int* vbuckP = ebuckP + NNZP;       // NNZ ints = 6.4 MB (total 12.8 <= 51.2)

    // workspace layout (~52.5 MB)
    ushort* Xp16 = (ushort*)d_ws;                        // N*D bf16
    ushort* Xe16 = Xp16 + (size_t)NN * DD;               // E*D bf16
    ushort* Wt16 = Xe16 + (size_t)NE * DD;               // D*D bf16
    int*    eoff = (int*)(Wt16 + DD * DD);               // E+1
    int*    voff = eoff + NE + 1;                        // N+1
    int*    vlist = voff + NN + 1;                       // NNZ
    int*    elist = vlist + NNZP;                        // NNZ
    int*    gCnt  = elist + NNZP;                        // NBT
    int*    eBase = gCnt + NBT;                          // NBE+1
    int*    vBase = eBase + NBE + 1;                     // NBV+1
    int*    blkCnt = vBase + NBV + 1;                    // NBT*NSB = 147000

    scatter_count<<<NSB + 64, 256, 0, stream>>>(vertex, edges, blkCnt, W, Wt16);
    gemm_mfma<<<(NN / 16 + 7) / 8, 256, 0, stream>>>(X, Wt16, Xp16);
    blk_scan<<<NBT, 256, 0, stream>>>(blkCnt, gCnt);
    bucket_scan<<<1, 512, 0, stream>>>(gCnt, eBase, vBase, eoff, voff);
    scatter_place<<<NSB, 256, 0, stream>>>(vertex, edges, blkCnt, eBase, vBase, ebuckP, vbuckP);
    place_buckets2<<<NBT, 256, 0, stream>>>(ebuckP, vbuckP, eBase, vBase, eoff, voff, vlist, elist);
    edge_gather<<<NE / 8, 256, 0, stream>>>(Xp16, eoff, vlist, Xe, Xe16);
    vertex_gather_out<<<NN / 8, 256, 0, stream>>>(Xp16, Xe16, voff, elist, eps, out);
}

// Round 13
// 209.590 us; speedup vs baseline: 1.6310x; 1.0186x over previous
//
#include <hip/hip_runtime.h>
#include <hip/hip_bf16.h>

#define NN   100000
#define NE   50000
#define NNZP 1600000
#define DD   128

#define EBK  512
#define NBE  ((NE + EBK - 1) / EBK)             // 98
#define VBK  512
#define NBV  ((NN + VBK - 1) / VBK)             // 196
#define NBT  (NBE + NBV)                        // 294
#define CH2  3200                               // pairs per scatter block
#define NSB  500                                // 500 * 3200 == NNZP
#define NGB  ((NN / 16 + 7) / 8)                // 782 gemm blocks

typedef __attribute__((ext_vector_type(8))) short bf16x8;
typedef __attribute__((ext_vector_type(4))) float f32x4;
typedef __attribute__((ext_vector_type(2))) unsigned int u32x2;

__device__ __forceinline__ ushort f2bf(float f) {
    __hip_bfloat16 h = __float2bfloat16(f);
    return *reinterpret_cast<ushort*>(&h);
}
__device__ __forceinline__ void accP(u32x2 u, float& ax, float& ay, float& az, float& aw) {
    ax += __uint_as_float(u.x << 16);
    ay += __uint_as_float(u.x & 0xffff0000u);
    az += __uint_as_float(u.y << 16);
    aw += __uint_as_float(u.y & 0xffff0000u);
}
__device__ __forceinline__ u32x2 ldg_u2(const ushort* p) {
    return *reinterpret_cast<const u32x2*>(p);
}

// exclusive scan of gCnt[0..NBT) into sbase (LDS); 256 threads, 2 elems/thread
__device__ __forceinline__ void scan_gcnt(const int* __restrict__ gCnt,
                                          int* sbase, int* wsum) {
    const int t = threadIdx.x;
    int c0 = (2 * t     < NBT) ? gCnt[2 * t]     : 0;
    int c1 = (2 * t + 1 < NBT) ? gCnt[2 * t + 1] : 0;
    int s = c0 + c1;
    int inc = s;
    #pragma unroll
    for (int d = 1; d < 64; d <<= 1) {
        int x = __shfl_up(inc, d, 64);
        if ((t & 63) >= d) inc += x;
    }
    if ((t & 63) == 63) wsum[t >> 6] = inc;
    __syncthreads();
    int wid = t >> 6, wbase = 0;
    #pragma unroll
    for (int w = 0; w < 3; ++w) if (w < wid) wbase += wsum[w];
    int excl = wbase + inc - s;
    if (2 * t     < NBT) sbase[2 * t]     = excl;
    if (2 * t + 1 < NBT) sbase[2 * t + 1] = excl + c0;
    __syncthreads();
}

// ------- K1: per-(bucket,block) counts, no global atomics; + Wt convert tail -------
__global__ __launch_bounds__(256) void scatter_count(const int* __restrict__ vertex,
                                                     const int* __restrict__ edges,
                                                     int* __restrict__ blkCnt,
                                                     const float* __restrict__ W,
                                                     ushort* __restrict__ Wt) {
    __shared__ int c[NBT];
    const int t = threadIdx.x;
    if (blockIdx.x >= NSB) {        // tail: Wt16[n][k] = bf16(W[k][n])
        int i = (blockIdx.x - NSB) * 256 + t;
        if (i < DD * DD) { int k = i >> 7, n = i & 127; Wt[n * DD + k] = f2bf(W[i]); }
        return;
    }
    for (int i = t; i < NBT; i += 256) c[i] = 0;
    __syncthreads();
    const int base = blockIdx.x * CH2;
    for (int i = t; i < CH2 / 4; i += 256) {
        int4 e4 = *reinterpret_cast<const int4*>(edges + base + i * 4);
        int4 v4 = *reinterpret_cast<const int4*>(vertex + base + i * 4);
        atomicAdd(&c[e4.x >> 9], 1); atomicAdd(&c[e4.y >> 9], 1);
        atomicAdd(&c[e4.z >> 9], 1); atomicAdd(&c[e4.w >> 9], 1);
        atomicAdd(&c[NBE + (v4.x >> 9)], 1); atomicAdd(&c[NBE + (v4.y >> 9)], 1);
        atomicAdd(&c[NBE + (v4.z >> 9)], 1); atomicAdd(&c[NBE + (v4.w >> 9)], 1);
    }
    __syncthreads();
    for (int i = t; i < NBT; i += 256) blkCnt[i * NSB + blockIdx.x] = c[i];
}

// ------- K2: per-bucket scan of 500 block counts -> relative offsets; total -> gCnt;
//             also writes the fixed CSR tails -------
__global__ __launch_bounds__(256) void blk_scan(int* __restrict__ blkCnt,
                                                int* __restrict__ gCnt,
                                                int* __restrict__ eoff,
                                                int* __restrict__ voff) {
    __shared__ int wsum[4];
    const int t = threadIdx.x;
    if (blockIdx.x == 0 && t == 0) { eoff[NE] = NNZP; voff[NN] = NNZP; }
    int* p = blkCnt + blockIdx.x * NSB;
    int c0 = (2 * t     < NSB) ? p[2 * t]     : 0;
    int c1 = (2 * t + 1 < NSB) ? p[2 * t + 1] : 0;
    int s = c0 + c1;
    int inc = s;
    #pragma unroll
    for (int d = 1; d < 64; d <<= 1) {
        int x = __shfl_up(inc, d, 64);
        if ((t & 63) >= d) inc += x;
    }
    if ((t & 63) == 63) wsum[t >> 6] = inc;
    __syncthreads();
    int wid = t >> 6, wbase = 0;
    #pragma unroll
    for (int w = 0; w < 3; ++w) if (w < wid) wbase += wsum[w];
    int excl = wbase + inc - s;
    if (2 * t     < NSB) p[2 * t]     = excl;
    if (2 * t + 1 < NSB) p[2 * t + 1] = excl + c0;
    if (t == 255) gCnt[blockIdx.x] = wbase + inc;   // bucket total
}

// ------- K3 (fused): blocks [0,NGB) = MFMA GEMM; blocks [NGB,NGB+NSB) = placement ----
// ebuckP[i] = (e&511)<<17 | v ; vbuckP[i] = (v&511)<<16 | e
__global__ __launch_bounds__(256) void place_gemm(const int* __restrict__ vertex,
                                                  const int* __restrict__ edges,
                                                  const int* __restrict__ blkCnt,
                                                  const int* __restrict__ gCnt,
                                                  unsigned int* __restrict__ ebuckP,
                                                  unsigned int* __restrict__ vbuckP,
                                                  const float* __restrict__ X,
                                                  const ushort* __restrict__ Wt,
                                                  ushort* __restrict__ Xp16) {
    __shared__ char smem[DD * DD * 2];   // 32 KB: WtL (gemm) | sbase+cur (placement)
    __shared__ int wsum[4];
    const int t = threadIdx.x;
    if (blockIdx.x < NGB) {
        // ---------------- GEMM: Xp16 = bf16( X @ W ), 2 rowTiles/wave ----------------
        char* WtL = smem;
        for (int c = t; c < 2048; c += 256) {
            int n = c >> 4, kc = c & 15;
            int dst = (n * 256 + kc * 16) ^ ((n & 7) << 4);
            *reinterpret_cast<int4*>(WtL + dst) = reinterpret_cast<const int4*>(Wt)[c];
        }
        __syncthreads();
        int wave = t >> 6;
        int lane = t & 63;
        int r = lane & 15, half = lane >> 4;
        #pragma unroll
        for (int rt = 0; rt < 2; ++rt) {
            int rowTile = blockIdx.x * 8 + wave * 2 + rt;
            if (rowTile >= NN / 16) break;
            const float* xrow = X + (size_t)(rowTile * 16 + r) * DD;
            f32x4 acc[8];
            #pragma unroll
            for (int nt = 0; nt < 8; ++nt) acc[nt] = (f32x4)(0.f);
            #pragma unroll
            for (int kk = 0; kk < DD; kk += 32) {
                int kbase = kk + half * 8;
                float4 xa = *reinterpret_cast<const float4*>(xrow + kbase);
                float4 xb = *reinterpret_cast<const float4*>(xrow + kbase + 4);
                bf16x8 a;
                a[0] = (short)f2bf(xa.x); a[1] = (short)f2bf(xa.y);
                a[2] = (short)f2bf(xa.z); a[3] = (short)f2bf(xa.w);
                a[4] = (short)f2bf(xb.x); a[5] = (short)f2bf(xb.y);
                a[6] = (short)f2bf(xb.z); a[7] = (short)f2bf(xb.w);
                #pragma unroll
                for (int nt = 0; nt < 8; ++nt) {
                    int n = nt * 16 + r;
                    int off = (n * 256 + kbase * 2) ^ ((n & 7) << 4);
                    bf16x8 b = *reinterpret_cast<const bf16x8*>(WtL + off);
                    acc[nt] = __builtin_amdgcn_mfma_f32_16x16x32_bf16(a, b, acc[nt], 0, 0, 0);
                }
            }
            int row0 = rowTile * 16 + half * 4;   // C/D: col=lane&15, row=(lane>>4)*4+q
            #pragma unroll
            for (int nt = 0; nt < 8; ++nt)
                #pragma unroll
                for (int q = 0; q < 4; ++q)
                    Xp16[(size_t)(row0 + q) * DD + nt * 16 + r] = f2bf(acc[nt][q]);
        }
    } else {
        // ---------------- placement with deterministic cursors ----------------
        const int pb = blockIdx.x - NGB;          // 0..NSB-1
        int* sbase = reinterpret_cast<int*>(smem);       // NBT
        int* cur   = sbase + NBT;                        // NBT
        scan_gcnt(gCnt, sbase, wsum);
        for (int i = t; i < NBT; i += 256) {
            int rel = blkCnt[i * NSB + pb];
            int b = sbase[i] - ((i < NBE) ? 0 : NNZP);
            cur[i] = b + rel;
        }
        __syncthreads();
        const int base = pb * CH2;
        for (int i = t; i < CH2 / 2; i += 256) {
            int2 e2 = *reinterpret_cast<const int2*>(edges + base + i * 2);
            int2 v2 = *reinterpret_cast<const int2*>(vertex + base + i * 2);
            int pe0 = atomicAdd(&cur[e2.x >> 9], 1);
            ebuckP[pe0] = ((unsigned)(e2.x & 511) << 17) | (unsigned)v2.x;
            int pe1 = atomicAdd(&cur[e2.y >> 9], 1);
            ebuckP[pe1] = ((unsigned)(e2.y & 511) << 17) | (unsigned)v2.y;
            int pv0 = atomicAdd(&cur[NBE + (v2.x >> 9)], 1);
            vbuckP[pv0] = ((unsigned)(v2.x & 511) << 16) | (unsigned)e2.x;
            int pv1 = atomicAdd(&cur[NBE + (v2.y >> 9)], 1);
            vbuckP[pv1] = ((unsigned)(v2.y & 511) << 16) | (unsigned)e2.y;
        }
    }
}

// ------- K4: per bucket: LDS per-id hist + scan -> eoff/voff, then place ----
__global__ __launch_bounds__(256) void place_buckets2(const unsigned int* __restrict__ ebuckP,
                                                      const unsigned int* __restrict__ vbuckP,
                                                      const int* __restrict__ gCnt,
                                                      int* __restrict__ eoff,
                                                      int* __restrict__ voff,
                                                      int* __restrict__ vlist,
                                                      int* __restrict__ elist) {
    __shared__ int sbase[NBT];
    __shared__ int cnt[EBK];
    __shared__ int wsum[4];
    const int t = threadIdx.x;
    scan_gcnt(gCnt, sbase, wsum);
    int b = blockIdx.x;
    const unsigned int* buck; int id0, nid, start, end; int* off; int* lst;
    int sh_amt; unsigned msk;
    if (b < NBE) {
        buck = ebuckP; id0 = b * EBK; nid = min(EBK, NE - id0);
        start = sbase[b]; end = start + gCnt[b]; off = eoff; lst = vlist;
        sh_amt = 17; msk = 0x1FFFFu;
    } else {
        buck = vbuckP; id0 = (b - NBE) * VBK; nid = min(VBK, NN - id0);
        start = sbase[b] - NNZP; end = start + gCnt[b]; off = voff; lst = elist;
        sh_amt = 16; msk = 0xFFFFu;
    }
    for (int i = t; i < nid; i += 256) cnt[i] = 0;
    __syncthreads();
    for (int i = start + t; i < end; i += 256)
        atomicAdd(&cnt[buck[i] >> sh_amt], 1);
    __syncthreads();
    int c0 = (2 * t     < nid) ? cnt[2 * t]     : 0;
    int c1 = (2 * t + 1 < nid) ? cnt[2 * t + 1] : 0;
    int s = c0 + c1;
    int inc = s;
    #pragma unroll
    for (int d = 1; d < 64; d <<= 1) {
        int x = __shfl_up(inc, d, 64);
        if ((t & 63) >= d) inc += x;
    }
    if ((t & 63) == 63) wsum[t >> 6] = inc;
    __syncthreads();
    int wid = t >> 6, wbase = 0;
    #pragma unroll
    for (int w = 0; w < 3; ++w) if (w < wid) wbase += wsum[w];
    int excl = start + wbase + (inc - s);
    if (2 * t     < nid) off[id0 + 2 * t]     = excl;
    if (2 * t + 1 < nid) off[id0 + 2 * t + 1] = excl + c0;
    __syncthreads();
    if (2 * t     < nid) cnt[2 * t]     = excl;
    if (2 * t + 1 < nid) cnt[2 * t + 1] = excl + c0;
    __syncthreads();
    for (int i = start + t; i < end; i += 256) {
        unsigned p = buck[i];
        lst[atomicAdd(&cnt[p >> sh_amt], 1)] = (int)(p & msk);
    }
}

// ---------------- K5: Xe[e] = mean of Xp16 rows; also Xe16 (8-deep) -------
__global__ __launch_bounds__(256) void edge_gather(const ushort* __restrict__ Xp16,
                                                   const int* __restrict__ eoff,
                                                   const int* __restrict__ vlist,
                                                   float* __restrict__ Xe,
                                                   ushort* __restrict__ Xe16) {
    int e = blockIdx.x * 8 + (threadIdx.x >> 5);
    if (e >= NE) return;
    int lane = threadIdx.x & 31;
    int start = eoff[e], end = eoff[e + 1];
    float ax = 0.f, ay = 0.f, az = 0.f, aw = 0.f;
    int j = start;
    for (; j + 7 < end; j += 8) {
        int v0 = vlist[j],     v1 = vlist[j + 1], v2 = vlist[j + 2], v3 = vlist[j + 3];
        int v4 = vlist[j + 4], v5 = vlist[j + 5], v6 = vlist[j + 6], v7 = vlist[j + 7];
        u32x2 u0 = ldg_u2(Xp16 + (size_t)v0 * DD + lane * 4);
        u32x2 u1 = ldg_u2(Xp16 + (size_t)v1 * DD + lane * 4);
        u32x2 u2 = ldg_u2(Xp16 + (size_t)v2 * DD + lane * 4);
        u32x2 u3 = ldg_u2(Xp16 + (size_t)v3 * DD + lane * 4);
        u32x2 u4 = ldg_u2(Xp16 + (size_t)v4 * DD + lane * 4);
        u32x2 u5 = ldg_u2(Xp16 + (size_t)v5 * DD + lane * 4);
        u32x2 u6 = ldg_u2(Xp16 + (size_t)v6 * DD + lane * 4);
        u32x2 u7 = ldg_u2(Xp16 + (size_t)v7 * DD + lane * 4);
        accP(u0, ax, ay, az, aw); accP(u1, ax, ay, az, aw);
        accP(u2, ax, ay, az, aw); accP(u3, ax, ay, az, aw);
        accP(u4, ax, ay, az, aw); accP(u5, ax, ay, az, aw);
        accP(u6, ax, ay, az, aw); accP(u7, ax, ay, az, aw);
    }
    for (; j < end; ++j) {
        u32x2 u = ldg_u2(Xp16 + (size_t)vlist[j] * DD + lane * 4);
        accP(u, ax, ay, az, aw);
    }
    float inv = 1.0f / fmaxf((float)(end - start), 1.0f);
    f32x4 o; o[0] = ax * inv; o[1] = ay * inv; o[2] = az * inv; o[3] = aw * inv;
    __builtin_nontemporal_store(o, reinterpret_cast<f32x4*>(Xe + (size_t)e * DD + lane * 4));
    ushort4 h;
    h.x = f2bf(o[0]); h.y = f2bf(o[1]); h.z = f2bf(o[2]); h.w = f2bf(o[3]);
    *reinterpret_cast<ushort4*>(Xe16 + (size_t)e * DD + lane * 4) = h;   // re-read by K6: cached
}

// -------- K6: Xv = sum Xe16 rows; out = normalize((1+eps)*Xp + Xv) (8-deep) --------
__global__ __launch_bounds__(256) void vertex_gather_out(const ushort* __restrict__ Xp16,
                                                         const ushort* __restrict__ Xe16,
                                                         const int* __restrict__ voff,
                                                         const int* __restrict__ elist,
                                                         const float* __restrict__ eps,
                                                         float* __restrict__ Out) {
    int v = blockIdx.x * 8 + (threadIdx.x >> 5);
    if (v >= NN) return;
    int lane = threadIdx.x & 31;
    int start = voff[v], end = voff[v + 1];
    float ax = 0.f, ay = 0.f, az = 0.f, aw = 0.f;
    int j = start;
    for (; j + 7 < end; j += 8) {
        int e0 = elist[j],     e1 = elist[j + 1], e2 = elist[j + 2], e3 = elist[j + 3];
        int e4 = elist[j + 4], e5 = elist[j + 5], e6 = elist[j + 6], e7 = elist[j + 7];
        u32x2 u0 = ldg_u2(Xe16 + (size_t)e0 * DD + lane * 4);
        u32x2 u1 = ldg_u2(Xe16 + (size_t)e1 * DD + lane * 4);
        u32x2 u2 = ldg_u2(Xe16 + (size_t)e2 * DD + lane * 4);
        u32x2 u3 = ldg_u2(Xe16 + (size_t)e3 * DD + lane * 4);
        u32x2 u4 = ldg_u2(Xe16 + (size_t)e4 * DD + lane * 4);
        u32x2 u5 = ldg_u2(Xe16 + (size_t)e5 * DD + lane * 4);
        u32x2 u6 = ldg_u2(Xe16 + (size_t)e6 * DD + lane * 4);
        u32x2 u7 = ldg_u2(Xe16 + (size_t)e7 * DD + lane * 4);
        accP(u0, ax, ay, az, aw); accP(u1, ax, ay, az, aw);
        accP(u2, ax, ay, az, aw); accP(u3, ax, ay, az, aw);
        accP(u4, ax, ay, az, aw); accP(u5, ax, ay, az, aw);
        accP(u6, ax, ay, az, aw); accP(u7, ax, ay, az, aw);
    }
    for (; j < end; ++j) {
        u32x2 u = ldg_u2(Xe16 + (size_t)elist[j] * DD + lane * 4);
        accP(u, ax, ay, az, aw);
    }
    float g = 1.0f + eps[0];
    u32x2 xp = __builtin_nontemporal_load(
        reinterpret_cast<const u32x2*>(Xp16 + (size_t)v * DD + lane * 4));  // sequential, read-once
    f32x4 o;
    o[0] = fmaf(g, __uint_as_float(xp.x << 16),         ax);
    o[1] = fmaf(g, __uint_as_float(xp.x & 0xffff0000u), ay);
    o[2] = fmaf(g, __uint_as_float(xp.y << 16),         az);
    o[3] = fmaf(g, __uint_as_float(xp.y & 0xffff0000u), aw);
    float ss = o[0] * o[0] + o[1] * o[1] + o[2] * o[2] + o[3] * o[3];
    #pragma unroll
    for (int off = 1; off < 32; off <<= 1) ss += __shfl_xor(ss, off, 64);
    float inv = 1.0f / fmaxf(sqrtf(ss), 1e-12f);
    o[0] *= inv; o[1] *= inv; o[2] *= inv; o[3] *= inv;
    __builtin_nontemporal_store(o, reinterpret_cast<f32x4*>(Out + (size_t)v * DD + lane * 4));
}

extern "C" void kernel_launch(void* const* d_in, const int* in_sizes, int n_in,
                              void* d_out, int out_size, void* d_ws, size_t ws_size,
                              hipStream_t stream) {
    const float* X      = (const float*)d_in[0];
    const float* W      = (const float*)d_in[1];
    const float* eps    = (const float*)d_in[2];
    const int*   vertex = (const int*)d_in[3];
    const int*   edges  = (const int*)d_in[4];

    float* out = (float*)d_out;                 // [N,D] — scratch for buckets until K6
    float* Xe  = out + (size_t)NN * DD;         // [E,D]

    // packed bucket arrays live in the 'out' region (dead until vertex_gather_out)
    unsigned int* ebuckP = (unsigned int*)out;  // NNZ ints = 6.4 MB
    unsigned int* vbuckP = ebuckP + NNZP;       // NNZ ints = 6.4 MB (total 12.8 <= 51.2)

    // workspace layout (~52.5 MB)
    ushort* Xp16 = (ushort*)d_ws;                        // N*D bf16
    ushort* Xe16 = Xp16 + (size_t)NN * DD;               // E*D bf16
    ushort* Wt16 = Xe16 + (size_t)NE * DD;               // D*D bf16
    int*    eoff = (int*)(Wt16 + DD * DD);               // E+1
    int*    voff = eoff + NE + 1;                        // N+1
    int*    vlist = voff + NN + 1;                       // NNZ
    int*    elist = vlist + NNZP;                        // NNZ
    int*    gCnt  = elist + NNZP;                        // NBT
    int*    blkCnt = gCnt + NBT;                         // NBT*NSB = 147000

    scatter_count<<<NSB + 64, 256, 0, stream>>>(vertex, edges, blkCnt, W, Wt16);
    blk_scan<<<NBT, 256, 0, stream>>>(blkCnt, gCnt, eoff, voff);
    place_gemm<<<NGB + NSB, 256, 0, stream>>>(vertex, edges, blkCnt, gCnt,
                                              ebuckP, vbuckP, X, Wt16, Xp16);
    place_buckets2<<<NBT, 256, 0, stream>>>(ebuckP, vbuckP, gCnt, eoff, voff, vlist, elist);
    edge_gather<<<NE / 8, 256, 0, stream>>>(Xp16, eoff, vlist, Xe, Xe16);
    vertex_gather_out<<<NN / 8, 256, 0, stream>>>(Xp16, Xe16, voff, elist, eps, out);
}